// Round 9
// baseline (97511.053 us; speedup 1.0000x reference)
//
#include <hip/hip_runtime.h>

namespace {
constexpr int B = 128;      // batch
constexpr int D = 80;       // mel dim
constexpr int H = 256;      // hidden
constexpr int PP = 128;     // prenet out
constexpr int TIN = 512;    // encoder steps
constexpr int RSTEPS = 200; // reduced steps
constexpr int RF = 5;       // reduction factor
}

__device__ __forceinline__ float sigm(float x) { return 1.f / (1.f + __expf(-x)); }
__device__ __forceinline__ float tanh_(float x) { return 1.f - 2.f / (__expf(2.f * x) + 1.f); }
__device__ __forceinline__ unsigned short f2bf(float f) {  // RNE
  unsigned int u = __float_as_uint(f);
  u += 0x7fffu + ((u >> 16) & 1u);
  return (unsigned short)(u >> 16);
}
__device__ __forceinline__ void bf2x(unsigned int w, float& f0, float& f1) {
  f0 = __uint_as_float(w << 16);
  f1 = __uint_as_float(w & 0xffff0000u);
}
__device__ __forceinline__ void unpack8(uint4 w, float* f) {
  bf2x(w.x, f[0], f[1]); bf2x(w.y, f[2], f[3]);
  bf2x(w.z, f[4], f[5]); bf2x(w.w, f[6], f[7]);
}
__device__ __forceinline__ float dot8(uint4 w, float4 x0, float4 x1) {
  float f0, f1, a;
  bf2x(w.x, f0, f1); a  = f0 * x0.x + f1 * x0.y;
  bf2x(w.y, f0, f1); a += f0 * x0.z + f1 * x0.w;
  bf2x(w.z, f0, f1); a += f0 * x1.x + f1 * x1.y;
  bf2x(w.w, f0, f1); a += f0 * x1.z + f1 * x1.w;
  return a;
}

// accumulate 3 gate rows (stride 256 cols) over NKG k-groups of 8
template <int NKG>
__device__ __forceinline__ void acc3(const uint4* __restrict__ wB, int j, int kg0,
                                     const float4* __restrict__ src4,
                                     float& a0, float& a1, float& a2) {
#pragma unroll
  for (int q = 0; q < NKG; ++q) {
    const int kg = kg0 + q;
    const float4 x0 = src4[kg * 2], x1 = src4[kg * 2 + 1];
    a0 += dot8(wB[(size_t)kg * 768 + j], x0, x1);
    a1 += dot8(wB[(size_t)kg * 768 + 256 + j], x0, x1);
    a2 += dot8(wB[(size_t)kg * 768 + 512 + j], x0, x1);
  }
}

// ---------------------------------------------------------------------------
__global__ __launch_bounds__(256) void k_keys(const float* __restrict__ mem,
                                              const float* __restrict__ Wm,
                                              unsigned short* __restrict__ keysB) {
  const int k = threadIdx.x;
  const int m0 = blockIdx.x * 32;
  const float* xb = mem + (size_t)m0 * H;
  float acc[32];
#pragma unroll
  for (int i = 0; i < 32; ++i) acc[i] = 0.f;
  for (int h = 0; h < H; h += 4) {
    const float w0 = Wm[(h + 0) * H + k];
    const float w1 = Wm[(h + 1) * H + k];
    const float w2 = Wm[(h + 2) * H + k];
    const float w3 = Wm[(h + 3) * H + k];
#pragma unroll
    for (int mi = 0; mi < 32; ++mi) {
      const float4 x = *reinterpret_cast<const float4*>(xb + (size_t)mi * H + h);
      acc[mi] += x.x * w0 + x.y * w1 + x.z * w2 + x.w * w3;
    }
  }
#pragma unroll
  for (int mi = 0; mi < 32; ++mi) {
    const int m = m0 + mi, t = m >> 7, bb = m & 127;
    keysB[((size_t)bb * TIN + t) * H + k] = f2bf(acc[mi]);
  }
}

__global__ __launch_bounds__(256) void k_memB(const float* __restrict__ mem,
                                              unsigned short* __restrict__ memB) {
  const int m = blockIdx.x, t = m >> 7, bb = m & 127;
  memB[((size_t)bb * TIN + t) * H + threadIdx.x] = f2bf(mem[(size_t)m * H + threadIdx.x]);
}

// pack W[K][C] -> bf16 [(k>>3)*C + c]*8 + (k&7)
__global__ __launch_bounds__(256) void k_pack8b(const float* __restrict__ W,
                                                unsigned short* __restrict__ Wp,
                                                int K, int C) {
  const int idx = blockIdx.x * 256 + threadIdx.x;
  if (idx >= K * C) return;
  const int k = idx / C, c = idx - k * C;
  Wp[((size_t)(k >> 3) * C + c) * 8 + (k & 7)] = f2bf(W[idx]);
}

__global__ __launch_bounds__(256) void k_prenet(
    const float* __restrict__ outs, const float* __restrict__ Wp0,
    const float* __restrict__ bp0, const float* __restrict__ Wp1,
    const float* __restrict__ bp1, unsigned short* __restrict__ preB) {
  const int t = blockIdx.x >> 7, b = blockIdx.x & 127, tid = threadIdx.x;
  __shared__ float f[80];
  __shared__ float p0[256];
  __shared__ float s2[256];
  if (tid < 80)
    f[tid] = (t == 0) ? 0.f
                      : __builtin_nontemporal_load(
                            &outs[((size_t)(t * RF - 1) * B + b) * D + tid]);
  __syncthreads();
  {
    float a = bp0[tid];
#pragma unroll 8
    for (int k = 0; k < 80; ++k) a += f[k] * Wp0[k * 256 + tid];
    p0[tid] = fmaxf(a, 0.f);
  }
  __syncthreads();
  {
    const int c = tid & 127, kh = tid >> 7;
    float a = 0.f;
#pragma unroll 8
    for (int k = kh * 128; k < kh * 128 + 128; ++k) a += p0[k] * Wp1[k * 128 + c];
    s2[kh * 128 + c] = a;
  }
  __syncthreads();
  if (tid < 128)
    preB[((size_t)t * B + b) * PP + tid] =
        f2bf(fmaxf(bp1[tid] + s2[tid] + s2[128 + tid], 0.f));
}

// ---------------------------------------------------------------------------
// Persistent per-batch-row block; all streams & GEMV weights bf16.
__global__ __launch_bounds__(1024, 4) void k_step(
    const unsigned short* __restrict__ memB, const unsigned short* __restrict__ keysB,
    const unsigned short* __restrict__ preB,
    const unsigned short* __restrict__ wxaB, const unsigned short* __restrict__ whaB,
    const float* __restrict__ b_att, const unsigned short* __restrict__ wqB,
    const float* __restrict__ v_att,
    const unsigned short* __restrict__ wxd0B, const unsigned short* __restrict__ whd0B,
    const float* __restrict__ b_d0,
    const unsigned short* __restrict__ wxd1B, const unsigned short* __restrict__ whd1B,
    const float* __restrict__ b_d1,
    const float* __restrict__ Wo, const float* __restrict__ bo,
    float* __restrict__ dout, float* __restrict__ alpha) {
  const int b = blockIdx.x;
  const int tid = threadIdx.x;
  const int lane = tid & 63, wv = tid >> 6;

  __shared__ alignas(16) float hA[256], hD0[256], hD1[256];
  __shared__ alignas(16) float ctx_l[256], res0_l[256], res1_l[256];
  __shared__ alignas(16) float pre_l[128];
  __shared__ float qk_p[16 * 18];
  __shared__ float v_p[16 * 18];
  __shared__ alignas(16) float scr[8192];
  __shared__ alignas(16) float ep[512];
  __shared__ float r16[16];
  __shared__ float bc[2];

  if (tid < 256) {
    hA[tid] = 0.f; hD0[tid] = 0.f; hD1[tid] = 0.f;
    v_p[(tid >> 4) * 18 + (tid & 15)] = v_att[tid];
  }
  __syncthreads();

  const float4* hA4 = reinterpret_cast<const float4*>(hA);
  const float4* hD04 = reinterpret_cast<const float4*>(hD0);
  const float4* hD14 = reinterpret_cast<const float4*>(hD1);
  const float4* ctx4 = reinterpret_cast<const float4*>(ctx_l);
  const float4* res04 = reinterpret_cast<const float4*>(res0_l);
  const float4* pre4 = reinterpret_cast<const float4*>(pre_l);
  const uint4* wA  = reinterpret_cast<const uint4*>(wxaB);
  const uint4* wAh = reinterpret_cast<const uint4*>(whaB);
  const uint4* w0x = reinterpret_cast<const uint4*>(wxd0B);
  const uint4* w0h = reinterpret_cast<const uint4*>(whd0B);
  const uint4* w1x = reinterpret_cast<const uint4*>(wxd1B);
  const uint4* w1h = reinterpret_cast<const uint4*>(whd1B);
  const uint4* wQ  = reinterpret_cast<const uint4*>(wqB);

  for (int t = 0; t < RSTEPS; ++t) {
    if (tid < PP)
      pre_l[tid] = __uint_as_float((unsigned)preB[((size_t)t * B + b) * PP + tid] << 16);
    __syncthreads();

    // ---- attention GRU: x(K=128, 16 kg) + h(K=256, 32 kg); thread (j, ks) ----
    {
      const int j = tid & 255, ks = tid >> 8;
      float pz = 0, pr = 0, px = 0, ph = 0;
      acc3<4>(wA, j, ks * 4, pre4, pz, pr, px);
      acc3<8>(wAh, j, ks * 8, hA4, pz, pr, ph);
      scr[ks * 1024 + j] = pz;       scr[ks * 1024 + 256 + j] = pr;
      scr[ks * 1024 + 512 + j] = px; scr[ks * 1024 + 768 + j] = ph;
    }
    __syncthreads();
    if (tid < 256) {
      float az = 0, ar = 0, acx = 0, ach = 0;
#pragma unroll
      for (int ks = 0; ks < 4; ++ks) {
        az += scr[ks * 1024 + tid];        ar += scr[ks * 1024 + 256 + tid];
        acx += scr[ks * 1024 + 512 + tid]; ach += scr[ks * 1024 + 768 + tid];
      }
      const float z = sigm(az + b_att[tid]);
      const float r = sigm(ar + b_att[256 + tid]);
      const float c = tanh_(acx + r * ach + b_att[512 + tid]);
      hA[tid] = (1.f - z) * hA[tid] + z * c;   // = query
    }
    __syncthreads();

    // ---- qW: K=256 (32 kg), 256 cols, bf16 ----
    {
      const int c = tid & 255, ks = tid >> 8;
      float a = 0.f;
#pragma unroll
      for (int q = 0; q < 8; ++q) {
        const int kg = ks * 8 + q;
        a += dot8(wQ[(size_t)kg * 256 + c], hA4[kg * 2], hA4[kg * 2 + 1]);
      }
      scr[ks * 256 + c] = a;
    }
    __syncthreads();
    if (tid < 256) {
      const float qv = scr[tid] + scr[256 + tid] + scr[512 + tid] + scr[768 + tid];
      qk_p[(tid >> 4) * 18 + (tid & 15)] = qv;
    }
    __syncthreads();

    // ---- e-pass: 64 groups x 16 lanes, bf16 keys, padded q/v (no conflicts) ----
    {
      const int l16 = tid & 15, g = tid >> 4;
      float qg[16], vg[16];
#pragma unroll
      for (int i = 0; i < 16; ++i) {
        qg[i] = qk_p[l16 * 18 + i];
        vg[i] = v_p[l16 * 18 + i];
      }
      const uint4* kB = reinterpret_cast<const uint4*>(keysB + (size_t)b * TIN * H);
#pragma unroll
      for (int p = 0; p < 4; ++p) {
        const int t1 = g + p * 128, t2 = t1 + 64;
        const uint4 a0 = kB[(size_t)t1 * 32 + l16 * 2], a1 = kB[(size_t)t1 * 32 + l16 * 2 + 1];
        const uint4 b0 = kB[(size_t)t2 * 32 + l16 * 2], b1 = kB[(size_t)t2 * 32 + l16 * 2 + 1];
        float ka[16], kb2[16];
        unpack8(a0, ka); unpack8(a1, ka + 8);
        unpack8(b0, kb2); unpack8(b1, kb2 + 8);
        float s1 = 0.f, s2 = 0.f;
#pragma unroll
        for (int i = 0; i < 16; ++i) {
          s1 += vg[i] * tanh_(ka[i] + qg[i]);
          s2 += vg[i] * tanh_(kb2[i] + qg[i]);
        }
#pragma unroll
        for (int m = 1; m < 16; m <<= 1) { s1 += __shfl_xor(s1, m, 16); s2 += __shfl_xor(s2, m, 16); }
        if (l16 == 0) { ep[t1] = s1; ep[t2] = s2; }
      }
    }
    __syncthreads();

    // ---- softmax over 512 ----
    float ev = -1e30f, pv = 0.f;
    if (tid < TIN) {
      ev = ep[tid];
      float mx = ev;
#pragma unroll
      for (int m = 1; m < 64; m <<= 1) mx = fmaxf(mx, __shfl_xor(mx, m));
      if (lane == 0) r16[wv] = mx;
    }
    __syncthreads();
    if (tid == 0) {
      float g = r16[0];
#pragma unroll
      for (int w = 1; w < 8; ++w) g = fmaxf(g, r16[w]);
      bc[0] = g;
    }
    __syncthreads();
    const float M = bc[0];
    if (tid < TIN) {
      pv = __expf(ev - M);
      ep[tid] = pv;
      float s = pv;
#pragma unroll
      for (int m = 1; m < 64; m <<= 1) s += __shfl_xor(s, m);
      if (lane == 0) r16[wv] = s;
    }
    __syncthreads();
    if (tid == 0) {
      float s = 0.f;
#pragma unroll
      for (int w = 0; w < 8; ++w) s += r16[w];
      bc[1] = 1.f / s;
    }
    __syncthreads();
    const float inv = bc[1];
    if (tid < TIN)
      __builtin_nontemporal_store(pv * inv, &alpha[((size_t)t * B + b) * TIN + tid]);

    // ---- context: bf16 memB; thread = (8 k's, 16 t's); 32-slice reduce ----
    {
      const int kq8 = tid & 31, ts = tid >> 5;
      float a[8] = {0.f, 0.f, 0.f, 0.f, 0.f, 0.f, 0.f, 0.f};
      const uint4* mB = reinterpret_cast<const uint4*>(memB + (size_t)b * TIN * H);
#pragma unroll 4
      for (int i = 0; i < 16; ++i) {
        const int tt = ts * 16 + i;
        const float p = ep[tt];
        float mv[8];
        unpack8(mB[(size_t)tt * 32 + kq8], mv);
#pragma unroll
        for (int j = 0; j < 8; ++j) a[j] += p * mv[j];
      }
      float4* s4 = reinterpret_cast<float4*>(scr + ts * 256 + kq8 * 8);
      s4[0] = make_float4(a[0], a[1], a[2], a[3]);
      s4[1] = make_float4(a[4], a[5], a[6], a[7]);
    }
    __syncthreads();
    if (tid < 256) {
      float s = 0.f;
#pragma unroll
      for (int ts2 = 0; ts2 < 32; ++ts2) s += scr[ts2 * 256 + tid];
      ctx_l[tid] = inv * s;
    }
    __syncthreads();

    // ---- decoder GRU 0: x=[query;ctx] (K=512, 64 kg) + h (K=256, 32 kg) ----
    {
      const int j = tid & 255, ks = tid >> 8;
      float pz = 0, pr = 0, px = 0, ph = 0;
      acc3<16>(w0x, j, ks * 16, (ks < 2) ? hA4 : (ctx4 - 64), pz, pr, px);
      acc3<8>(w0h, j, ks * 8, hD04, pz, pr, ph);
      scr[ks * 1024 + j] = pz;       scr[ks * 1024 + 256 + j] = pr;
      scr[ks * 1024 + 512 + j] = px; scr[ks * 1024 + 768 + j] = ph;
    }
    __syncthreads();
    if (tid < 256) {
      float az = 0, ar = 0, acx = 0, ach = 0;
#pragma unroll
      for (int ks = 0; ks < 4; ++ks) {
        az += scr[ks * 1024 + tid];        ar += scr[ks * 1024 + 256 + tid];
        acx += scr[ks * 1024 + 512 + tid]; ach += scr[ks * 1024 + 768 + tid];
      }
      const float z = sigm(az + b_d0[tid]);
      const float r = sigm(ar + b_d0[256 + tid]);
      const float c = tanh_(acx + r * ach + b_d0[512 + tid]);
      const float hn = (1.f - z) * hD0[tid] + z * c;
      hD0[tid] = hn;
      res0_l[tid] = hA[tid] + hn;
    }
    __syncthreads();

    // ---- decoder GRU 1: x=res0 (32 kg) + h (32 kg) ----
    {
      const int j = tid & 255, ks = tid >> 8;
      float pz = 0, pr = 0, px = 0, ph = 0;
      acc3<8>(w1x, j, ks * 8, res04, pz, pr, px);
      acc3<8>(w1h, j, ks * 8, hD14, pz, pr, ph);
      scr[ks * 1024 + j] = pz;       scr[ks * 1024 + 256 + j] = pr;
      scr[ks * 1024 + 512 + j] = px; scr[ks * 1024 + 768 + j] = ph;
    }
    __syncthreads();
    if (tid < 256) {
      float az = 0, ar = 0, acx = 0, ach = 0;
#pragma unroll
      for (int ks = 0; ks < 4; ++ks) {
        az += scr[ks * 1024 + tid];        ar += scr[ks * 1024 + 256 + tid];
        acx += scr[ks * 1024 + 512 + tid]; ach += scr[ks * 1024 + 768 + tid];
      }
      const float z = sigm(az + b_d1[tid]);
      const float r = sigm(ar + b_d1[256 + tid]);
      const float c = tanh_(acx + r * ach + b_d1[512 + tid]);
      const float hn = (1.f - z) * hD1[tid] + z * c;
      hD1[tid] = hn;
      res1_l[tid] = res0_l[tid] + hn;
    }
    __syncthreads();

    // ---- dense: fp32 Wo, 80 cols, 8 K-slices -> 5 output frames (NT) ----
    {
      const int c = tid & 127, ks = tid >> 7;
      float a = 0.f;
      if (c < D) {
#pragma unroll 8
        for (int k = ks * 32; k < ks * 32 + 32; ++k) a += res1_l[k] * Wo[k * D + c];
      }
      scr[ks * 128 + c] = a;
    }
    __syncthreads();
    if (tid < D) {
      float dv = bo[tid];
#pragma unroll
      for (int ks = 0; ks < 8; ++ks) dv += scr[ks * 128 + tid];
      const size_t base = (size_t)t * RF * (B * D) + (size_t)b * D + tid;
#pragma unroll
      for (int i = 0; i < RF; ++i)
        __builtin_nontemporal_store(dv, &dout[base + (size_t)i * (B * D)]);
    }
    __syncthreads();
  }
}

// ---------------------------------------------------------------------------
extern "C" void kernel_launch(void* const* d_in, const int* in_sizes, int n_in,
                              void* d_out, int out_size, void* d_ws,
                              size_t ws_size, hipStream_t stream) {
  const float* outs   = (const float*)d_in[0];
  const float* memory = (const float*)d_in[1];
  const float* Wp0    = (const float*)d_in[2];
  const float* bp0    = (const float*)d_in[3];
  const float* Wp1    = (const float*)d_in[4];
  const float* bp1    = (const float*)d_in[5];
  const float* Wx_att = (const float*)d_in[6];
  const float* Wh_att = (const float*)d_in[7];
  const float* b_att  = (const float*)d_in[8];
  const float* Wq     = (const float*)d_in[9];
  const float* Wm     = (const float*)d_in[10];
  const float* v_att  = (const float*)d_in[11];
  const float* Wx_d0  = (const float*)d_in[12];
  const float* Wh_d0  = (const float*)d_in[13];
  const float* b_d0   = (const float*)d_in[14];
  const float* Wx_d1  = (const float*)d_in[15];
  const float* Wh_d1  = (const float*)d_in[16];
  const float* b_d1   = (const float*)d_in[17];
  const float* Wo     = (const float*)d_in[18];
  const float* bo     = (const float*)d_in[19];
  float* dout = (float*)d_out;
  unsigned short* wsb = (unsigned short*)d_ws;

  size_t off = 0;
  unsigned short* keysB = wsb + off; off += (size_t)TIN * B * H;
  unsigned short* memB  = wsb + off; off += (size_t)TIN * B * H;
  unsigned short* preB  = wsb + off; off += (size_t)RSTEPS * B * PP;
  unsigned short* wqB   = wsb + off; off += (size_t)256 * 256;
  unsigned short* wxaB  = wsb + off; off += (size_t)128 * 768;
  unsigned short* whaB  = wsb + off; off += (size_t)256 * 768;
  unsigned short* wxd0B = wsb + off; off += (size_t)512 * 768;
  unsigned short* whd0B = wsb + off; off += (size_t)256 * 768;
  unsigned short* wxd1B = wsb + off; off += (size_t)256 * 768;
  unsigned short* whd1B = wsb + off; off += (size_t)256 * 768;

  k_keys<<<(TIN * B) / 32, 256, 0, stream>>>(memory, Wm, keysB);
  k_memB<<<TIN * B, 256, 0, stream>>>(memory, memB);
  k_prenet<<<RSTEPS * B, 256, 0, stream>>>(outs, Wp0, bp0, Wp1, bp1, preB);
  k_pack8b<<<(256 * 256 + 255) / 256, 256, 0, stream>>>(Wq, wqB, 256, 256);
  k_pack8b<<<(128 * 768 + 255) / 256, 256, 0, stream>>>(Wx_att, wxaB, 128, 768);
  k_pack8b<<<(256 * 768 + 255) / 256, 256, 0, stream>>>(Wh_att, whaB, 256, 768);
  k_pack8b<<<(512 * 768 + 255) / 256, 256, 0, stream>>>(Wx_d0, wxd0B, 512, 768);
  k_pack8b<<<(256 * 768 + 255) / 256, 256, 0, stream>>>(Wh_d0, whd0B, 256, 768);
  k_pack8b<<<(256 * 768 + 255) / 256, 256, 0, stream>>>(Wx_d1, wxd1B, 256, 768);
  k_pack8b<<<(256 * 768 + 255) / 256, 256, 0, stream>>>(Wh_d1, whd1B, 256, 768);

  float* alpha = dout + (size_t)1000 * B * D;
  k_step<<<B, 1024, 0, stream>>>(memB, keysB, preB,
                                 wxaB, whaB, b_att, wqB, v_att,
                                 wxd0B, whd0B, b_d0, wxd1B, whd1B, b_d1,
                                 Wo, bo, dout, alpha);
}

// Round 10
// 11955.009 us; speedup vs baseline: 8.1565x; 8.1565x over previous
//
#include <hip/hip_runtime.h>

namespace {
constexpr int B = 128;      // batch
constexpr int D = 80;       // mel dim
constexpr int H = 256;      // hidden
constexpr int PP = 128;     // prenet out
constexpr int TIN = 512;    // encoder steps
constexpr int RSTEPS = 200; // reduced steps
constexpr int RF = 5;       // reduction factor
}

__device__ __forceinline__ float sigm(float x) { return 1.f / (1.f + __expf(-x)); }
__device__ __forceinline__ float tanh_(float x) { return 1.f - 2.f / (__expf(2.f * x) + 1.f); }
__device__ __forceinline__ unsigned short f2bf(float f) {  // RNE
  unsigned int u = __float_as_uint(f);
  u += 0x7fffu + ((u >> 16) & 1u);
  return (unsigned short)(u >> 16);
}
__device__ __forceinline__ void bf2x(unsigned int w, float& f0, float& f1) {
  f0 = __uint_as_float(w << 16);
  f1 = __uint_as_float(w & 0xffff0000u);
}
__device__ __forceinline__ void unpack8(uint4 w, float* f) {
  bf2x(w.x, f[0], f[1]); bf2x(w.y, f[2], f[3]);
  bf2x(w.z, f[4], f[5]); bf2x(w.w, f[6], f[7]);
}
__device__ __forceinline__ float dot8(uint4 w, float4 x0, float4 x1) {
  float f0, f1, a;
  bf2x(w.x, f0, f1); a  = f0 * x0.x + f1 * x0.y;
  bf2x(w.y, f0, f1); a += f0 * x0.z + f1 * x0.w;
  bf2x(w.z, f0, f1); a += f0 * x1.x + f1 * x1.y;
  bf2x(w.w, f0, f1); a += f0 * x1.z + f1 * x1.w;
  return a;
}

// ---------------------------------------------------------------------------
// keysB[b,t,k] = bf16( sum_h memory[t,b,h] * Wm[h,k] )
__global__ __launch_bounds__(256) void k_keys(const float* __restrict__ mem,
                                              const float* __restrict__ Wm,
                                              unsigned short* __restrict__ keysB) {
  const int k = threadIdx.x;
  const int m0 = blockIdx.x * 32;
  const float* xb = mem + (size_t)m0 * H;
  float acc[32];
#pragma unroll
  for (int i = 0; i < 32; ++i) acc[i] = 0.f;
  for (int h = 0; h < H; h += 4) {
    const float w0 = Wm[(h + 0) * H + k];
    const float w1 = Wm[(h + 1) * H + k];
    const float w2 = Wm[(h + 2) * H + k];
    const float w3 = Wm[(h + 3) * H + k];
#pragma unroll
    for (int mi = 0; mi < 32; ++mi) {
      const float4 x = *reinterpret_cast<const float4*>(xb + (size_t)mi * H + h);
      acc[mi] += x.x * w0 + x.y * w1 + x.z * w2 + x.w * w3;
    }
  }
#pragma unroll
  for (int mi = 0; mi < 32; ++mi) {
    const int m = m0 + mi, t = m >> 7, bb = m & 127;
    keysB[((size_t)bb * TIN + t) * H + k] = f2bf(acc[mi]);
  }
}

__global__ __launch_bounds__(256) void k_memB(const float* __restrict__ mem,
                                              unsigned short* __restrict__ memB) {
  const int m = blockIdx.x, t = m >> 7, bb = m & 127;
  memB[((size_t)bb * TIN + t) * H + threadIdx.x] = f2bf(mem[(size_t)m * H + threadIdx.x]);
}

// pack Wq[256][256] -> bf16 [(k>>3)*256 + c]*8 + (k&7)
__global__ __launch_bounds__(256) void k_packWq(const float* __restrict__ W,
                                                unsigned short* __restrict__ Wp) {
  const int idx = blockIdx.x * 256 + threadIdx.x;
  const int k = idx >> 8, c = idx & 255;
  Wp[(((size_t)(k >> 3) * 256) + c) * 8 + (k & 7)] = f2bf(W[idx]);
}

// pack GRU weight W[K][768] (cols z|r|c) into row-interleaved bf16:
// dst[(rowOff+k)*1024 + (j>>1)*8 + (j&1)*4 + g]; slots 3,7 are pad.
__global__ __launch_bounds__(256) void k_packG(const float* __restrict__ W,
                                               unsigned short* __restrict__ dst,
                                               int K, int rowOff) {
  const int idx = blockIdx.x * 256 + threadIdx.x;
  if (idx >= K * 768) return;
  const int k = idx / 768, c = idx - k * 768;
  const int g = c >> 8, j = c & 255;
  dst[((size_t)(rowOff + k) * 128 + (j >> 1)) * 8 + (j & 1) * 4 + g] = f2bf(W[idx]);
}

// Hoisted prenet -> preT[t][j][b] fp32
__global__ __launch_bounds__(256) void k_prenet(
    const float* __restrict__ outs, const float* __restrict__ Wp0,
    const float* __restrict__ bp0, const float* __restrict__ Wp1,
    const float* __restrict__ bp1, float* __restrict__ preT) {
  const int t = blockIdx.x >> 7, b = blockIdx.x & 127, tid = threadIdx.x;
  __shared__ float f[80];
  __shared__ float p0[256];
  __shared__ float s2[256];
  if (tid < 80)
    f[tid] = (t == 0) ? 0.f
                      : __builtin_nontemporal_load(
                            &outs[((size_t)(t * RF - 1) * B + b) * D + tid]);
  __syncthreads();
  {
    float a = bp0[tid];
#pragma unroll 8
    for (int k = 0; k < 80; ++k) a += f[k] * Wp0[k * 256 + tid];
    p0[tid] = fmaxf(a, 0.f);
  }
  __syncthreads();
  {
    const int c = tid & 127, kh = tid >> 7;
    float a = 0.f;
#pragma unroll 8
    for (int k = kh * 128; k < kh * 128 + 128; ++k) a += p0[k] * Wp1[k * 128 + c];
    s2[kh * 128 + c] = a;
  }
  __syncthreads();
  if (tid < 128)
    preT[((size_t)t * PP + tid) * B + b] = fmaxf(bp1[tid] + s2[tid] + s2[128 + tid], 0.f);
}

// ---------------------------------------------------------------------------
// j-parallel GRU: blocks 0..255 -> (jg2 = blk>>1 owns j {2jg2, 2jg2+1}, bh = blk&1).
// 16 waves split the K1(x1)+K2(x2)+KH(h) reduction; one uint4 bf16 weight row
// load per k (2 j x 3 gates). Blocks 256..383 (when launched): dense for t-1.
__global__ __launch_bounds__(1024) void k_gru(
    const unsigned short* __restrict__ wp, int K1, int K2, int KH,
    const float* __restrict__ xT1, const float* __restrict__ xT2,
    const float* __restrict__ hT_old, const float* __restrict__ b3,
    float* __restrict__ hT_new, const float* __restrict__ resInT,
    float* __restrict__ resOutT, int t,
    const float* __restrict__ res1T, const float* __restrict__ Wo,
    const float* __restrict__ bo, float* __restrict__ dout) {
  const int tid = threadIdx.x;
  __shared__ float part[16 * 512];
  __shared__ float red[512];

  if (blockIdx.x >= 256) {             // ---- dense for step t-1 ----
    const int b = blockIdx.x - 256;
    if (t == 0) return;
    if (tid < 256) red[tid] = res1T[tid * B + b];
    __syncthreads();
    {
      const int ks = tid >> 7, c = tid & 127;
      float a = 0.f;
      if (c < D) {
#pragma unroll 8
        for (int k = ks * 32; k < ks * 32 + 32; ++k) a += red[k] * Wo[k * D + c];
      }
      part[ks * 128 + c] = a;
    }
    __syncthreads();
    if (tid < D) {
      float dv = bo[tid];
#pragma unroll
      for (int ks = 0; ks < 8; ++ks) dv += part[ks * 128 + tid];
      const size_t base = (size_t)(t - 1) * RF * (B * D) + (size_t)b * D + tid;
#pragma unroll
      for (int i = 0; i < RF; ++i)
        __builtin_nontemporal_store(dv, &dout[base + (size_t)i * (B * D)]);
    }
    return;
  }
  if (t >= RSTEPS) return;             // final launch: dense-only

  const int blk = blockIdx.x;
  const int jg2 = blk >> 1, bh = blk & 1;
  const int lane = tid & 63, wv = tid >> 6;
  const int b = bh * 64 + lane;

  const uint4* wp4 = reinterpret_cast<const uint4*>(wp);
  const int K12 = K1 + K2, KT = K12 + KH;
  const int KS = KT >> 4;
  const int k0 = wv * KS, k1 = k0 + KS;

  float az0 = 0, ar0 = 0, acx0 = 0, ach0 = 0;
  float az1 = 0, ar1 = 0, acx1 = 0, ach1 = 0;
  float f0, f1;

  const int e1 = (k1 < K1) ? k1 : K1;
#pragma unroll 4
  for (int k = k0; k < e1; ++k) {
    const uint4 w = wp4[(size_t)k * 128 + jg2];
    const float x = xT1[k * B + b];
    bf2x(w.x, f0, f1); az0 += f0 * x; ar0 += f1 * x;
    bf2x(w.y, f0, f1); acx0 += f0 * x;
    bf2x(w.z, f0, f1); az1 += f0 * x; ar1 += f1 * x;
    bf2x(w.w, f0, f1); acx1 += f0 * x;
  }
  const int s2 = (k0 > K1) ? k0 : K1, e2 = (k1 < K12) ? k1 : K12;
#pragma unroll 4
  for (int k = s2; k < e2; ++k) {
    const uint4 w = wp4[(size_t)k * 128 + jg2];
    const float x = xT2[(k - K1) * B + b];
    bf2x(w.x, f0, f1); az0 += f0 * x; ar0 += f1 * x;
    bf2x(w.y, f0, f1); acx0 += f0 * x;
    bf2x(w.z, f0, f1); az1 += f0 * x; ar1 += f1 * x;
    bf2x(w.w, f0, f1); acx1 += f0 * x;
  }
  const int s3 = (k0 > K12) ? k0 : K12;
#pragma unroll 4
  for (int k = s3; k < k1; ++k) {
    const uint4 w = wp4[(size_t)k * 128 + jg2];
    const float x = hT_old[(k - K12) * B + b];
    bf2x(w.x, f0, f1); az0 += f0 * x; ar0 += f1 * x;
    bf2x(w.y, f0, f1); ach0 += f0 * x;
    bf2x(w.z, f0, f1); az1 += f0 * x; ar1 += f1 * x;
    bf2x(w.w, f0, f1); ach1 += f0 * x;
  }

  float* pw = part + wv * 512;
  pw[0 * 64 + lane] = az0;  pw[1 * 64 + lane] = ar0;
  pw[2 * 64 + lane] = acx0; pw[3 * 64 + lane] = ach0;
  pw[4 * 64 + lane] = az1;  pw[5 * 64 + lane] = ar1;
  pw[6 * 64 + lane] = acx1; pw[7 * 64 + lane] = ach1;
  __syncthreads();
  if (tid < 512) {
    float s = 0.f;
#pragma unroll
    for (int w = 0; w < 16; ++w) s += part[w * 512 + tid];
    red[tid] = s;
  }
  __syncthreads();
  if (tid < 128) {
    const int jl = tid >> 6, ln = tid & 63;
    const int j = jg2 * 2 + jl;
    const int bb = bh * 64 + ln;
    const float az = red[(jl * 4 + 0) * 64 + ln];
    const float ar = red[(jl * 4 + 1) * 64 + ln];
    const float acx = red[(jl * 4 + 2) * 64 + ln];
    const float ach = red[(jl * 4 + 3) * 64 + ln];
    const float z = sigm(az + b3[j]);
    const float r = sigm(ar + b3[H + j]);
    const float c = tanh_(acx + r * ach + b3[2 * H + j]);
    const float hold = hT_old[j * B + bb];
    const float hn = (1.f - z) * hold + z * c;
    hT_new[j * B + bb] = hn;
    if (resOutT) resOutT[j * B + bb] = resInT[j * B + bb] + hn;
  }
}

// ---------------------------------------------------------------------------
// Per-b attention: qW (bf16) + e-pass (bf16 keys, padded q/v) + softmax +
// alpha + context (bf16 mem) -> ctxT. grid = B, 1024 threads.
__global__ __launch_bounds__(1024) void k_attn(
    int t, const float* __restrict__ qT, const unsigned short* __restrict__ wqB,
    const float* __restrict__ v_att, const unsigned short* __restrict__ keysB,
    const unsigned short* __restrict__ memB, float* __restrict__ ctxT,
    float* __restrict__ alpha) {
  const int b = blockIdx.x;
  const int tid = threadIdx.x;
  const int lane = tid & 63, wv = tid >> 6;

  __shared__ alignas(16) float hA[256];
  __shared__ float qk_p[16 * 18];
  __shared__ float v_p[16 * 18];
  __shared__ alignas(16) float scr[8192];
  __shared__ alignas(16) float ep[512];
  __shared__ float r16[16];
  __shared__ float bc[2];

  if (tid < 256) {
    hA[tid] = qT[tid * B + b];
    v_p[(tid >> 4) * 18 + (tid & 15)] = v_att[tid];
  }
  __syncthreads();
  const float4* hA4 = reinterpret_cast<const float4*>(hA);
  const uint4* wQ = reinterpret_cast<const uint4*>(wqB);

  {  // qW
    const int c = tid & 255, ks = tid >> 8;
    float a = 0.f;
#pragma unroll
    for (int q = 0; q < 8; ++q) {
      const int kg = ks * 8 + q;
      a += dot8(wQ[(size_t)kg * 256 + c], hA4[kg * 2], hA4[kg * 2 + 1]);
    }
    scr[ks * 256 + c] = a;
  }
  __syncthreads();
  if (tid < 256)
    qk_p[(tid >> 4) * 18 + (tid & 15)] =
        scr[tid] + scr[256 + tid] + scr[512 + tid] + scr[768 + tid];
  __syncthreads();

  {  // e-pass
    const int l16 = tid & 15, g = tid >> 4;
    float qg[16], vg[16];
#pragma unroll
    for (int i = 0; i < 16; ++i) {
      qg[i] = qk_p[l16 * 18 + i];
      vg[i] = v_p[l16 * 18 + i];
    }
    const uint4* kB = reinterpret_cast<const uint4*>(keysB + (size_t)b * TIN * H);
#pragma unroll
    for (int p = 0; p < 4; ++p) {
      const int t1 = g + p * 128, t2 = t1 + 64;
      const uint4 a0 = kB[(size_t)t1 * 32 + l16 * 2], a1 = kB[(size_t)t1 * 32 + l16 * 2 + 1];
      const uint4 b0 = kB[(size_t)t2 * 32 + l16 * 2], b1 = kB[(size_t)t2 * 32 + l16 * 2 + 1];
      float ka[16], kb2[16];
      unpack8(a0, ka); unpack8(a1, ka + 8);
      unpack8(b0, kb2); unpack8(b1, kb2 + 8);
      float s1 = 0.f, s2 = 0.f;
#pragma unroll
      for (int i = 0; i < 16; ++i) {
        s1 += vg[i] * tanh_(ka[i] + qg[i]);
        s2 += vg[i] * tanh_(kb2[i] + qg[i]);
      }
#pragma unroll
      for (int m = 1; m < 16; m <<= 1) { s1 += __shfl_xor(s1, m, 16); s2 += __shfl_xor(s2, m, 16); }
      if (l16 == 0) { ep[t1] = s1; ep[t2] = s2; }
    }
  }
  __syncthreads();

  // softmax over 512
  float ev = -1e30f, pv = 0.f;
  if (tid < TIN) {
    ev = ep[tid];
    float mx = ev;
#pragma unroll
    for (int m = 1; m < 64; m <<= 1) mx = fmaxf(mx, __shfl_xor(mx, m));
    if (lane == 0) r16[wv] = mx;
  }
  __syncthreads();
  if (tid == 0) {
    float g = r16[0];
#pragma unroll
    for (int w = 1; w < 8; ++w) g = fmaxf(g, r16[w]);
    bc[0] = g;
  }
  __syncthreads();
  const float M = bc[0];
  if (tid < TIN) {
    pv = __expf(ev - M);
    ep[tid] = pv;
    float s = pv;
#pragma unroll
    for (int m = 1; m < 64; m <<= 1) s += __shfl_xor(s, m);
    if (lane == 0) r16[wv] = s;
  }
  __syncthreads();
  if (tid == 0) {
    float s = 0.f;
#pragma unroll
    for (int w = 0; w < 8; ++w) s += r16[w];
    bc[1] = 1.f / s;
  }
  __syncthreads();
  const float inv = bc[1];
  if (tid < TIN)
    __builtin_nontemporal_store(pv * inv, &alpha[((size_t)t * B + b) * TIN + tid]);

  {  // context
    const int kq8 = tid & 31, ts = tid >> 5;
    float a[8] = {0.f, 0.f, 0.f, 0.f, 0.f, 0.f, 0.f, 0.f};
    const uint4* mB = reinterpret_cast<const uint4*>(memB + (size_t)b * TIN * H);
#pragma unroll 4
    for (int i = 0; i < 16; ++i) {
      const int tt = ts * 16 + i;
      const float p = ep[tt];
      float mv[8];
      unpack8(mB[(size_t)tt * 32 + kq8], mv);
#pragma unroll
      for (int j = 0; j < 8; ++j) a[j] += p * mv[j];
    }
    float4* s4 = reinterpret_cast<float4*>(scr + ts * 256 + kq8 * 8);
    s4[0] = make_float4(a[0], a[1], a[2], a[3]);
    s4[1] = make_float4(a[4], a[5], a[6], a[7]);
  }
  __syncthreads();
  if (tid < 256) {
    float s = 0.f;
#pragma unroll
    for (int ts2 = 0; ts2 < 32; ++ts2) s += scr[ts2 * 256 + tid];
    ctxT[tid * B + b] = inv * s;
  }
}

// ---------------------------------------------------------------------------
extern "C" void kernel_launch(void* const* d_in, const int* in_sizes, int n_in,
                              void* d_out, int out_size, void* d_ws,
                              size_t ws_size, hipStream_t stream) {
  const float* outs   = (const float*)d_in[0];
  const float* memory = (const float*)d_in[1];
  const float* Wp0    = (const float*)d_in[2];
  const float* bp0    = (const float*)d_in[3];
  const float* Wp1    = (const float*)d_in[4];
  const float* bp1    = (const float*)d_in[5];
  const float* Wx_att = (const float*)d_in[6];
  const float* Wh_att = (const float*)d_in[7];
  const float* b_att  = (const float*)d_in[8];
  const float* Wq     = (const float*)d_in[9];
  const float* Wm     = (const float*)d_in[10];
  const float* v_att  = (const float*)d_in[11];
  const float* Wx_d0  = (const float*)d_in[12];
  const float* Wh_d0  = (const float*)d_in[13];
  const float* b_d0   = (const float*)d_in[14];
  const float* Wx_d1  = (const float*)d_in[15];
  const float* Wh_d1  = (const float*)d_in[16];
  const float* b_d1   = (const float*)d_in[17];
  const float* Wo     = (const float*)d_in[18];
  const float* bo     = (const float*)d_in[19];
  float* dout = (float*)d_out;
  float* wsf  = (float*)d_ws;

  size_t off = 0;  // in floats
  unsigned short* keysB = (unsigned short*)(wsf + off); off += (size_t)TIN * B * H / 2;
  unsigned short* memB  = (unsigned short*)(wsf + off); off += (size_t)TIN * B * H / 2;
  unsigned short* wqB   = (unsigned short*)(wsf + off); off += (size_t)256 * 256 / 2;
  unsigned short* wgA   = (unsigned short*)(wsf + off); off += (size_t)384 * 1024 / 2;
  unsigned short* wg0   = (unsigned short*)(wsf + off); off += (size_t)768 * 1024 / 2;
  unsigned short* wg1   = (unsigned short*)(wsf + off); off += (size_t)512 * 1024 / 2;
  float* preT = wsf + off; off += (size_t)RSTEPS * PP * B;
  float* qbuf[2];
  qbuf[0] = wsf + off; off += (size_t)H * B;
  qbuf[1] = wsf + off; off += (size_t)H * B;
  float* hd0b[2];
  hd0b[0] = wsf + off; off += (size_t)H * B;
  hd0b[1] = wsf + off; off += (size_t)H * B;
  float* hd1b[2];
  hd1b[0] = wsf + off; off += (size_t)H * B;
  hd1b[1] = wsf + off; off += (size_t)H * B;
  float* ctxT  = wsf + off; off += (size_t)H * B;
  float* res0T = wsf + off; off += (size_t)H * B;
  float* res1T = wsf + off; off += (size_t)H * B;

  hipMemsetAsync(qbuf[0], 0, (size_t)H * B * sizeof(float), stream);
  hipMemsetAsync(hd0b[0], 0, (size_t)H * B * sizeof(float), stream);
  hipMemsetAsync(hd1b[0], 0, (size_t)H * B * sizeof(float), stream);

  k_keys<<<(TIN * B) / 32, 256, 0, stream>>>(memory, Wm, keysB);
  k_memB<<<TIN * B, 256, 0, stream>>>(memory, memB);
  k_prenet<<<RSTEPS * B, 256, 0, stream>>>(outs, Wp0, bp0, Wp1, bp1, preT);
  k_packWq<<<256, 256, 0, stream>>>(Wq, wqB);
  k_packG<<<(128 * 768 + 255) / 256, 256, 0, stream>>>(Wx_att, wgA, 128, 0);
  k_packG<<<(256 * 768 + 255) / 256, 256, 0, stream>>>(Wh_att, wgA, 256, 128);
  k_packG<<<(512 * 768 + 255) / 256, 256, 0, stream>>>(Wx_d0, wg0, 512, 0);
  k_packG<<<(256 * 768 + 255) / 256, 256, 0, stream>>>(Wh_d0, wg0, 256, 512);
  k_packG<<<(256 * 768 + 255) / 256, 256, 0, stream>>>(Wx_d1, wg1, 256, 0);
  k_packG<<<(256 * 768 + 255) / 256, 256, 0, stream>>>(Wh_d1, wg1, 256, 256);

  float* alpha = dout + (size_t)1000 * B * D;

  for (int t = 0; t < RSTEPS; ++t) {
    const int pi = t & 1, po = 1 - pi;
    // attention GRU (blocks 0..255) + dense of step t-1 (blocks 256..383)
    k_gru<<<384, 1024, 0, stream>>>(wgA, PP, 0, H,
                                    preT + (size_t)t * PP * B, nullptr, qbuf[pi],
                                    b_att, qbuf[po], nullptr, nullptr,
                                    t, res1T, Wo, bo, dout);
    // attention: qW + e + softmax + alpha + context
    k_attn<<<B, 1024, 0, stream>>>(t, qbuf[po], wqB, v_att, keysB, memB,
                                   ctxT, alpha);
    // decoder GRU 0: x = [query; ctx], res0 = query + out0
    k_gru<<<256, 1024, 0, stream>>>(wg0, H, H, H,
                                    qbuf[po], ctxT, hd0b[pi],
                                    b_d0, hd0b[po], qbuf[po], res0T,
                                    t, nullptr, nullptr, nullptr, nullptr);
    // decoder GRU 1: x = res0, res1 = res0 + out1
    k_gru<<<256, 1024, 0, stream>>>(wg1, H, 0, H,
                                    res0T, nullptr, hd1b[pi],
                                    b_d1, hd1b[po], res0T, res1T,
                                    t, nullptr, nullptr, nullptr, nullptr);
  }
  // final dense for step 199 (dense blocks only; main blocks skip via t==RSTEPS)
  k_gru<<<384, 1024, 0, stream>>>(wgA, PP, 0, H,
                                  preT, nullptr, qbuf[0],
                                  b_att, qbuf[1], nullptr, nullptr,
                                  RSTEPS, res1T, Wo, bo, dout);
}

// Round 11
// 9988.781 us; speedup vs baseline: 9.7621x; 1.1968x over previous
//
#include <hip/hip_runtime.h>

namespace {
constexpr int B = 128;      // batch
constexpr int D = 80;       // mel dim
constexpr int H = 256;      // hidden
constexpr int PP = 128;     // prenet out
constexpr int TIN = 512;    // encoder steps
constexpr int RSTEPS = 200; // reduced steps
constexpr int RF = 5;       // reduction factor
constexpr int HB = H * B;   // ring slot stride
}

__device__ __forceinline__ float sigm(float x) { return 1.f / (1.f + __expf(-x)); }
__device__ __forceinline__ float tanh_(float x) { return 1.f - 2.f / (__expf(2.f * x) + 1.f); }
__device__ __forceinline__ unsigned short f2bf(float f) {  // RNE
  unsigned int u = __float_as_uint(f);
  u += 0x7fffu + ((u >> 16) & 1u);
  return (unsigned short)(u >> 16);
}
__device__ __forceinline__ void bf2x(unsigned int w, float& f0, float& f1) {
  f0 = __uint_as_float(w << 16);
  f1 = __uint_as_float(w & 0xffff0000u);
}
__device__ __forceinline__ void unpack8(uint4 w, float* f) {
  bf2x(w.x, f[0], f[1]); bf2x(w.y, f[2], f[3]);
  bf2x(w.z, f[4], f[5]); bf2x(w.w, f[6], f[7]);
}
__device__ __forceinline__ float dot8(uint4 w, float4 x0, float4 x1) {
  float f0, f1, a;
  bf2x(w.x, f0, f1); a  = f0 * x0.x + f1 * x0.y;
  bf2x(w.y, f0, f1); a += f0 * x0.z + f1 * x0.w;
  bf2x(w.z, f0, f1); a += f0 * x1.x + f1 * x1.y;
  bf2x(w.w, f0, f1); a += f0 * x1.z + f1 * x1.w;
  return a;
}

// ---------------------------------------------------------------------------
// keysB[b,t,k] = bf16( sum_h memory[t,b,h] * Wm[h,k] )
__global__ __launch_bounds__(256) void k_keys(const float* __restrict__ mem,
                                              const float* __restrict__ Wm,
                                              unsigned short* __restrict__ keysB) {
  const int k = threadIdx.x;
  const int m0 = blockIdx.x * 32;
  const float* xb = mem + (size_t)m0 * H;
  float acc[32];
#pragma unroll
  for (int i = 0; i < 32; ++i) acc[i] = 0.f;
  for (int h = 0; h < H; h += 4) {
    const float w0 = Wm[(h + 0) * H + k];
    const float w1 = Wm[(h + 1) * H + k];
    const float w2 = Wm[(h + 2) * H + k];
    const float w3 = Wm[(h + 3) * H + k];
#pragma unroll
    for (int mi = 0; mi < 32; ++mi) {
      const float4 x = *reinterpret_cast<const float4*>(xb + (size_t)mi * H + h);
      acc[mi] += x.x * w0 + x.y * w1 + x.z * w2 + x.w * w3;
    }
  }
#pragma unroll
  for (int mi = 0; mi < 32; ++mi) {
    const int m = m0 + mi, t = m >> 7, bb = m & 127;
    keysB[((size_t)bb * TIN + t) * H + k] = f2bf(acc[mi]);
  }
}

__global__ __launch_bounds__(256) void k_memB(const float* __restrict__ mem,
                                              unsigned short* __restrict__ memB) {
  const int m = blockIdx.x, t = m >> 7, bb = m & 127;
  memB[((size_t)bb * TIN + t) * H + threadIdx.x] = f2bf(mem[(size_t)m * H + threadIdx.x]);
}

// pack Wq[256][256] -> bf16 [(k>>3)*256 + c]*8 + (k&7)
__global__ __launch_bounds__(256) void k_packWq(const float* __restrict__ W,
                                                unsigned short* __restrict__ Wp) {
  const int idx = blockIdx.x * 256 + threadIdx.x;
  const int k = idx >> 8, c = idx & 255;
  Wp[(((size_t)(k >> 3) * 256) + c) * 8 + (k & 7)] = f2bf(W[idx]);
}

// pack GRU weight W[K][768] (cols z|r|c) into row-interleaved bf16:
// dst[(rowOff+k)*1024 + (j>>1)*8 + (j&1)*4 + g]; slots 3,7 are pad.
__global__ __launch_bounds__(256) void k_packG(const float* __restrict__ W,
                                               unsigned short* __restrict__ dst,
                                               int K, int rowOff) {
  const int idx = blockIdx.x * 256 + threadIdx.x;
  if (idx >= K * 768) return;
  const int k = idx / 768, c = idx - k * 768;
  const int g = c >> 8, j = c & 255;
  dst[((size_t)(rowOff + k) * 128 + (j >> 1)) * 8 + (j & 1) * 4 + g] = f2bf(W[idx]);
}

// Hoisted prenet -> preT[t][j][b] fp32
__global__ __launch_bounds__(256) void k_prenet(
    const float* __restrict__ outs, const float* __restrict__ Wp0,
    const float* __restrict__ bp0, const float* __restrict__ Wp1,
    const float* __restrict__ bp1, float* __restrict__ preT) {
  const int t = blockIdx.x >> 7, b = blockIdx.x & 127, tid = threadIdx.x;
  __shared__ float f[80];
  __shared__ float p0[256];
  __shared__ float s2[256];
  if (tid < 80)
    f[tid] = (t == 0) ? 0.f
                      : __builtin_nontemporal_load(
                            &outs[((size_t)(t * RF - 1) * B + b) * D + tid]);
  __syncthreads();
  {
    float a = bp0[tid];
#pragma unroll 8
    for (int k = 0; k < 80; ++k) a += f[k] * Wp0[k * 256 + tid];
    p0[tid] = fmaxf(a, 0.f);
  }
  __syncthreads();
  {
    const int c = tid & 127, kh = tid >> 7;
    float a = 0.f;
#pragma unroll 8
    for (int k = kh * 128; k < kh * 128 + 128; ++k) a += p0[k] * Wp1[k * 128 + c];
    s2[kh * 128 + c] = a;
  }
  __syncthreads();
  if (tid < 128)
    preT[((size_t)t * PP + tid) * B + b] = fmaxf(bp1[tid] + s2[tid] + s2[128 + tid], 0.f);
}

// ---------------------------------------------------------------------------
// GRU body: rel in [0,256) -> (jg2 = rel>>1 owns j {2jg2,2jg2+1}, bh = rel&1).
// 16 waves split K1(x1)+K2(x2)+KH(h); one uint4 bf16 row load per k.
__device__ void gru_body(const unsigned short* __restrict__ wp, int K1, int K2,
                         int KH, const float* __restrict__ xT1,
                         const float* __restrict__ xT2,
                         const float* __restrict__ hT_old,
                         const float* __restrict__ b3, float* __restrict__ hT_new,
                         const float* __restrict__ resInT,
                         float* __restrict__ resOutT, int rel, float* smem) {
  const int tid = threadIdx.x;
  float* part = smem;            // 16*512
  float* red = smem + 8192;      // 512
  const int jg2 = rel >> 1, bh = rel & 1;
  const int lane = tid & 63, wv = tid >> 6;
  const int b = bh * 64 + lane;

  const uint4* wp4 = reinterpret_cast<const uint4*>(wp);
  const int K12 = K1 + K2, KT = K12 + KH;
  const int KS = KT >> 4;
  const int k0 = wv * KS, k1 = k0 + KS;

  float az0 = 0, ar0 = 0, acx0 = 0, ach0 = 0;
  float az1 = 0, ar1 = 0, acx1 = 0, ach1 = 0;
  float f0, f1;

  const int e1 = (k1 < K1) ? k1 : K1;
#pragma unroll 4
  for (int k = k0; k < e1; ++k) {
    const uint4 w = wp4[(size_t)k * 128 + jg2];
    const float x = xT1[k * B + b];
    bf2x(w.x, f0, f1); az0 += f0 * x; ar0 += f1 * x;
    bf2x(w.y, f0, f1); acx0 += f0 * x;
    bf2x(w.z, f0, f1); az1 += f0 * x; ar1 += f1 * x;
    bf2x(w.w, f0, f1); acx1 += f0 * x;
  }
  const int s2 = (k0 > K1) ? k0 : K1, e2 = (k1 < K12) ? k1 : K12;
#pragma unroll 4
  for (int k = s2; k < e2; ++k) {
    const uint4 w = wp4[(size_t)k * 128 + jg2];
    const float x = xT2[(k - K1) * B + b];
    bf2x(w.x, f0, f1); az0 += f0 * x; ar0 += f1 * x;
    bf2x(w.y, f0, f1); acx0 += f0 * x;
    bf2x(w.z, f0, f1); az1 += f0 * x; ar1 += f1 * x;
    bf2x(w.w, f0, f1); acx1 += f0 * x;
  }
  const int s3 = (k0 > K12) ? k0 : K12;
#pragma unroll 4
  for (int k = s3; k < k1; ++k) {
    const uint4 w = wp4[(size_t)k * 128 + jg2];
    const float x = hT_old[(k - K12) * B + b];
    bf2x(w.x, f0, f1); az0 += f0 * x; ar0 += f1 * x;
    bf2x(w.y, f0, f1); ach0 += f0 * x;
    bf2x(w.z, f0, f1); az1 += f0 * x; ar1 += f1 * x;
    bf2x(w.w, f0, f1); ach1 += f0 * x;
  }

  float* pw = part + wv * 512;
  pw[0 * 64 + lane] = az0;  pw[1 * 64 + lane] = ar0;
  pw[2 * 64 + lane] = acx0; pw[3 * 64 + lane] = ach0;
  pw[4 * 64 + lane] = az1;  pw[5 * 64 + lane] = ar1;
  pw[6 * 64 + lane] = acx1; pw[7 * 64 + lane] = ach1;
  __syncthreads();
  if (tid < 512) {
    float s = 0.f;
#pragma unroll
    for (int w = 0; w < 16; ++w) s += part[w * 512 + tid];
    red[tid] = s;
  }
  __syncthreads();
  if (tid < 128) {
    const int jl = tid >> 6, ln = tid & 63;
    const int j = jg2 * 2 + jl;
    const int bb = bh * 64 + ln;
    const float az = red[(jl * 4 + 0) * 64 + ln];
    const float ar = red[(jl * 4 + 1) * 64 + ln];
    const float acx = red[(jl * 4 + 2) * 64 + ln];
    const float ach = red[(jl * 4 + 3) * 64 + ln];
    const float z = sigm(az + b3[j]);
    const float r = sigm(ar + b3[H + j]);
    const float c = tanh_(acx + r * ach + b3[2 * H + j]);
    const float hold = hT_old[j * B + bb];
    const float hn = (1.f - z) * hold + z * c;
    hT_new[j * B + bb] = hn;
    if (resOutT) resOutT[j * B + bb] = resInT[j * B + bb] + hn;
  }
}

// dense for step s, batch row b: res1T -> 5 output frames
__device__ void dense_body(int s, int b, const float* __restrict__ res1T,
                           const float* __restrict__ Wo,
                           const float* __restrict__ bo, float* __restrict__ dout,
                           float* smem) {
  const int tid = threadIdx.x;
  float* red = smem;             // 256
  float* part = smem + 512;      // 1024
  if (tid < 256) red[tid] = res1T[tid * B + b];
  __syncthreads();
  {
    const int ks = tid >> 7, c = tid & 127;
    float a = 0.f;
    if (c < D) {
#pragma unroll 8
      for (int k = ks * 32; k < ks * 32 + 32; ++k) a += red[k] * Wo[k * D + c];
    }
    part[ks * 128 + c] = a;
  }
  __syncthreads();
  if (tid < D) {
    float dv = bo[tid];
#pragma unroll
    for (int ks = 0; ks < 8; ++ks) dv += part[ks * 128 + tid];
    const size_t base = (size_t)s * RF * (B * D) + (size_t)b * D + tid;
#pragma unroll
    for (int i = 0; i < RF; ++i)
      __builtin_nontemporal_store(dv, &dout[base + (size_t)i * (B * D)]);
  }
}

// attention body for (t, b): qW + e-pass + softmax + alpha + context
__device__ void attn_body(int t, int b, const float* __restrict__ qT,
                          const unsigned short* __restrict__ wqB,
                          const float* __restrict__ v_att,
                          const unsigned short* __restrict__ keysB,
                          const unsigned short* __restrict__ memB,
                          float* __restrict__ ctxT, float* __restrict__ alpha,
                          float* smem) {
  const int tid = threadIdx.x;
  const int lane = tid & 63, wv = tid >> 6;
  float* hA = smem;              // 256
  float* qk_p = smem + 256;      // 288
  float* v_p = smem + 544;       // 288
  float* scr = smem + 832;       // 8192
  float* ep = smem + 9024;       // 512
  float* r16 = smem + 9536;      // 16
  float* bc = smem + 9552;       // 2

  if (tid < 256) {
    hA[tid] = qT[tid * B + b];
    v_p[(tid >> 4) * 18 + (tid & 15)] = v_att[tid];
  }
  __syncthreads();
  const float4* hA4 = reinterpret_cast<const float4*>(hA);
  const uint4* wQ = reinterpret_cast<const uint4*>(wqB);

  {  // qW
    const int c = tid & 255, ks = tid >> 8;
    float a = 0.f;
#pragma unroll
    for (int q = 0; q < 8; ++q) {
      const int kg = ks * 8 + q;
      a += dot8(wQ[(size_t)kg * 256 + c], hA4[kg * 2], hA4[kg * 2 + 1]);
    }
    scr[ks * 256 + c] = a;
  }
  __syncthreads();
  if (tid < 256)
    qk_p[(tid >> 4) * 18 + (tid & 15)] =
        scr[tid] + scr[256 + tid] + scr[512 + tid] + scr[768 + tid];
  __syncthreads();

  {  // e-pass
    const int l16 = tid & 15, g = tid >> 4;
    float qg[16], vg[16];
#pragma unroll
    for (int i = 0; i < 16; ++i) {
      qg[i] = qk_p[l16 * 18 + i];
      vg[i] = v_p[l16 * 18 + i];
    }
    const uint4* kB = reinterpret_cast<const uint4*>(keysB + (size_t)b * TIN * H);
#pragma unroll
    for (int p = 0; p < 4; ++p) {
      const int t1 = g + p * 128, t2 = t1 + 64;
      const uint4 a0 = kB[(size_t)t1 * 32 + l16 * 2], a1 = kB[(size_t)t1 * 32 + l16 * 2 + 1];
      const uint4 b0 = kB[(size_t)t2 * 32 + l16 * 2], b1 = kB[(size_t)t2 * 32 + l16 * 2 + 1];
      float ka[16], kb2[16];
      unpack8(a0, ka); unpack8(a1, ka + 8);
      unpack8(b0, kb2); unpack8(b1, kb2 + 8);
      float s1 = 0.f, s2 = 0.f;
#pragma unroll
      for (int i = 0; i < 16; ++i) {
        s1 += vg[i] * tanh_(ka[i] + qg[i]);
        s2 += vg[i] * tanh_(kb2[i] + qg[i]);
      }
#pragma unroll
      for (int m = 1; m < 16; m <<= 1) { s1 += __shfl_xor(s1, m, 16); s2 += __shfl_xor(s2, m, 16); }
      if (l16 == 0) { ep[t1] = s1; ep[t2] = s2; }
    }
  }
  __syncthreads();

  // softmax over 512
  float ev = -1e30f, pv = 0.f;
  if (tid < TIN) {
    ev = ep[tid];
    float mx = ev;
#pragma unroll
    for (int m = 1; m < 64; m <<= 1) mx = fmaxf(mx, __shfl_xor(mx, m));
    if (lane == 0) r16[wv] = mx;
  }
  __syncthreads();
  if (tid == 0) {
    float g = r16[0];
#pragma unroll
    for (int w = 1; w < 8; ++w) g = fmaxf(g, r16[w]);
    bc[0] = g;
  }
  __syncthreads();
  const float M = bc[0];
  if (tid < TIN) {
    pv = __expf(ev - M);
    ep[tid] = pv;
    float s = pv;
#pragma unroll
    for (int m = 1; m < 64; m <<= 1) s += __shfl_xor(s, m);
    if (lane == 0) r16[wv] = s;
  }
  __syncthreads();
  if (tid == 0) {
    float s = 0.f;
#pragma unroll
    for (int w = 0; w < 8; ++w) s += r16[w];
    bc[1] = 1.f / s;
  }
  __syncthreads();
  const float inv = bc[1];
  if (tid < TIN)
    __builtin_nontemporal_store(pv * inv, &alpha[((size_t)t * B + b) * TIN + tid]);

  {  // context
    const int kq8 = tid & 31, ts = tid >> 5;
    float a[8] = {0.f, 0.f, 0.f, 0.f, 0.f, 0.f, 0.f, 0.f};
    const uint4* mB = reinterpret_cast<const uint4*>(memB + (size_t)b * TIN * H);
#pragma unroll 4
    for (int i = 0; i < 16; ++i) {
      const int tt = ts * 16 + i;
      const float p = ep[tt];
      float mv[8];
      unpack8(mB[(size_t)tt * 32 + kq8], mv);
#pragma unroll
      for (int j = 0; j < 8; ++j) a[j] += p * mv[j];
    }
    float4* s4 = reinterpret_cast<float4*>(scr + ts * 256 + kq8 * 8);
    s4[0] = make_float4(a[0], a[1], a[2], a[3]);
    s4[1] = make_float4(a[4], a[5], a[6], a[7]);
  }
  __syncthreads();
  if (tid < 256) {
    float s = 0.f;
#pragma unroll
    for (int ts2 = 0; ts2 < 32; ++ts2) s += scr[ts2 * 256 + tid];
    ctxT[tid * B + b] = inv * s;
  }
}

// ---------------------------------------------------------------------------
// Pipelined stage 1: attGRU(t) [0..255] + d0(t-1) [256..511] + dense(t-2) [512..639]
__global__ __launch_bounds__(1024) void k_s1(
    int t, const unsigned short* __restrict__ wgA,
    const unsigned short* __restrict__ wg0, const float* __restrict__ b_att,
    const float* __restrict__ b_d0, const float* __restrict__ preT,
    float* __restrict__ qr, float* __restrict__ ctxr, float* __restrict__ hd0r,
    float* __restrict__ res0r, const float* __restrict__ res1r,
    const float* __restrict__ Wo, const float* __restrict__ bo,
    float* __restrict__ dout) {
  __shared__ alignas(16) float smem[9600];
  const int blk = blockIdx.x;
  if (blk < 256) {
    if (t < RSTEPS)
      gru_body(wgA, PP, 0, H, preT + (size_t)t * PP * B, nullptr,
               qr + ((t + 1) & 1) * HB, b_att, qr + (t & 1) * HB, nullptr,
               nullptr, blk, smem);
  } else if (blk < 512) {
    const int s = t - 1;
    if (s >= 0 && s < RSTEPS)
      gru_body(wg0, H, H, H, qr + (s & 1) * HB, ctxr + (s & 1) * HB,
               hd0r + ((s + 1) & 1) * HB, b_d0, hd0r + (s & 1) * HB,
               qr + (s & 1) * HB, res0r + (s & 1) * HB, blk - 256, smem);
  } else {
    const int s = t - 2;
    if (s >= 0 && s < RSTEPS)
      dense_body(s, blk - 512, res1r + (s & 1) * HB, Wo, bo, dout, smem);
  }
}

// Pipelined stage 2: attn(t) [0..127] + d1(t-1) [128..383]
__global__ __launch_bounds__(1024) void k_s2(
    int t, const unsigned short* __restrict__ wqB,
    const unsigned short* __restrict__ wg1, const float* __restrict__ v_att,
    const float* __restrict__ b_d1, const unsigned short* __restrict__ keysB,
    const unsigned short* __restrict__ memB, const float* __restrict__ qr,
    float* __restrict__ ctxr, float* __restrict__ hd1r,
    const float* __restrict__ res0r, float* __restrict__ res1r,
    float* __restrict__ alpha) {
  __shared__ alignas(16) float smem[9600];
  const int blk = blockIdx.x;
  if (blk < 128) {
    if (t < RSTEPS)
      attn_body(t, blk, qr + (t & 1) * HB, wqB, v_att, keysB, memB,
                ctxr + (t & 1) * HB, alpha, smem);
  } else {
    const int s = t - 1;
    if (s >= 0 && s < RSTEPS)
      gru_body(wg1, H, 0, H, res0r + (s & 1) * HB, nullptr,
               hd1r + ((s + 1) & 1) * HB, b_d1, hd1r + (s & 1) * HB,
               res0r + (s & 1) * HB, res1r + (s & 1) * HB, blk - 128, smem);
  }
}

// ---------------------------------------------------------------------------
extern "C" void kernel_launch(void* const* d_in, const int* in_sizes, int n_in,
                              void* d_out, int out_size, void* d_ws,
                              size_t ws_size, hipStream_t stream) {
  const float* outs   = (const float*)d_in[0];
  const float* memory = (const float*)d_in[1];
  const float* Wp0    = (const float*)d_in[2];
  const float* bp0    = (const float*)d_in[3];
  const float* Wp1    = (const float*)d_in[4];
  const float* bp1    = (const float*)d_in[5];
  const float* Wx_att = (const float*)d_in[6];
  const float* Wh_att = (const float*)d_in[7];
  const float* b_att  = (const float*)d_in[8];
  const float* Wq     = (const float*)d_in[9];
  const float* Wm     = (const float*)d_in[10];
  const float* v_att  = (const float*)d_in[11];
  const float* Wx_d0  = (const float*)d_in[12];
  const float* Wh_d0  = (const float*)d_in[13];
  const float* b_d0   = (const float*)d_in[14];
  const float* Wx_d1  = (const float*)d_in[15];
  const float* Wh_d1  = (const float*)d_in[16];
  const float* b_d1   = (const float*)d_in[17];
  const float* Wo     = (const float*)d_in[18];
  const float* bo     = (const float*)d_in[19];
  float* dout = (float*)d_out;
  float* wsf  = (float*)d_ws;

  size_t off = 0;  // in floats
  unsigned short* keysB = (unsigned short*)(wsf + off); off += (size_t)TIN * B * H / 2;
  unsigned short* memB  = (unsigned short*)(wsf + off); off += (size_t)TIN * B * H / 2;
  unsigned short* wqB   = (unsigned short*)(wsf + off); off += (size_t)256 * 256 / 2;
  unsigned short* wgA   = (unsigned short*)(wsf + off); off += (size_t)384 * 1024 / 2;
  unsigned short* wg0   = (unsigned short*)(wsf + off); off += (size_t)768 * 1024 / 2;
  unsigned short* wg1   = (unsigned short*)(wsf + off); off += (size_t)512 * 1024 / 2;
  float* preT  = wsf + off; off += (size_t)RSTEPS * PP * B;
  float* qr    = wsf + off; off += (size_t)2 * HB;
  float* ctxr  = wsf + off; off += (size_t)2 * HB;
  float* hd0r  = wsf + off; off += (size_t)2 * HB;
  float* hd1r  = wsf + off; off += (size_t)2 * HB;
  float* res0r = wsf + off; off += (size_t)2 * HB;
  float* res1r = wsf + off; off += (size_t)2 * HB;

  // zero the ring slots read at the pipeline head (slot 1 of q/hd0/hd1)
  hipMemsetAsync(qr + HB, 0, (size_t)HB * sizeof(float), stream);
  hipMemsetAsync(hd0r + HB, 0, (size_t)HB * sizeof(float), stream);
  hipMemsetAsync(hd1r + HB, 0, (size_t)HB * sizeof(float), stream);

  k_keys<<<(TIN * B) / 32, 256, 0, stream>>>(memory, Wm, keysB);
  k_memB<<<TIN * B, 256, 0, stream>>>(memory, memB);
  k_prenet<<<RSTEPS * B, 256, 0, stream>>>(outs, Wp0, bp0, Wp1, bp1, preT);
  k_packWq<<<256, 256, 0, stream>>>(Wq, wqB);
  k_packG<<<(128 * 768 + 255) / 256, 256, 0, stream>>>(Wx_att, wgA, 128, 0);
  k_packG<<<(256 * 768 + 255) / 256, 256, 0, stream>>>(Wh_att, wgA, 256, 128);
  k_packG<<<(512 * 768 + 255) / 256, 256, 0, stream>>>(Wx_d0, wg0, 512, 0);
  k_packG<<<(256 * 768 + 255) / 256, 256, 0, stream>>>(Wh_d0, wg0, 256, 512);
  k_packG<<<(256 * 768 + 255) / 256, 256, 0, stream>>>(Wx_d1, wg1, 256, 0);
  k_packG<<<(256 * 768 + 255) / 256, 256, 0, stream>>>(Wh_d1, wg1, 256, 256);

  float* alpha = dout + (size_t)1000 * B * D;

  for (int t = 0; t <= RSTEPS + 1; ++t) {
    k_s1<<<640, 1024, 0, stream>>>(t, wgA, wg0, b_att, b_d0, preT, qr, ctxr,
                                   hd0r, res0r, res1r, Wo, bo, dout);
    if (t <= RSTEPS)
      k_s2<<<384, 1024, 0, stream>>>(t, wqB, wg1, v_att, b_d1, keysB, memB,
                                     qr, ctxr, hd1r, res0r, res1r, alpha);
  }
}

// Round 12
// 8857.201 us; speedup vs baseline: 11.0092x; 1.1278x over previous
//
#include <hip/hip_runtime.h>

namespace {
constexpr int B = 128;      // batch
constexpr int D = 80;       // mel dim
constexpr int H = 256;      // hidden
constexpr int PP = 128;     // prenet out
constexpr int TIN = 512;    // encoder steps
constexpr int RSTEPS = 200; // reduced steps
constexpr int RF = 5;       // reduction factor
constexpr int HB = H * B;   // ring slot stride
}

__device__ __forceinline__ float sigm(float x) { return 1.f / (1.f + __expf(-x)); }
__device__ __forceinline__ float tanh_(float x) { return 1.f - 2.f / (__expf(2.f * x) + 1.f); }
__device__ __forceinline__ unsigned short f2bf(float f) {  // RNE
  unsigned int u = __float_as_uint(f);
  u += 0x7fffu + ((u >> 16) & 1u);
  return (unsigned short)(u >> 16);
}
__device__ __forceinline__ void bf2x(unsigned int w, float& f0, float& f1) {
  f0 = __uint_as_float(w << 16);
  f1 = __uint_as_float(w & 0xffff0000u);
}
__device__ __forceinline__ void unpack8(uint4 w, float* f) {
  bf2x(w.x, f[0], f[1]); bf2x(w.y, f[2], f[3]);
  bf2x(w.z, f[4], f[5]); bf2x(w.w, f[6], f[7]);
}
__device__ __forceinline__ float dot8(uint4 w, float4 x0, float4 x1) {
  float f0, f1, a;
  bf2x(w.x, f0, f1); a  = f0 * x0.x + f1 * x0.y;
  bf2x(w.y, f0, f1); a += f0 * x0.z + f1 * x0.w;
  bf2x(w.z, f0, f1); a += f0 * x1.x + f1 * x1.y;
  bf2x(w.w, f0, f1); a += f0 * x1.z + f1 * x1.w;
  return a;
}

// ---------------------------------------------------------------------------
// keysB[b,t,k] = bf16( sum_h memory[t,b,h] * Wm[h,k] )
__global__ __launch_bounds__(256) void k_keys(const float* __restrict__ mem,
                                              const float* __restrict__ Wm,
                                              unsigned short* __restrict__ keysB) {
  const int k = threadIdx.x;
  const int m0 = blockIdx.x * 32;
  const float* xb = mem + (size_t)m0 * H;
  float acc[32];
#pragma unroll
  for (int i = 0; i < 32; ++i) acc[i] = 0.f;
  for (int h = 0; h < H; h += 4) {
    const float w0 = Wm[(h + 0) * H + k];
    const float w1 = Wm[(h + 1) * H + k];
    const float w2 = Wm[(h + 2) * H + k];
    const float w3 = Wm[(h + 3) * H + k];
#pragma unroll
    for (int mi = 0; mi < 32; ++mi) {
      const float4 x = *reinterpret_cast<const float4*>(xb + (size_t)mi * H + h);
      acc[mi] += x.x * w0 + x.y * w1 + x.z * w2 + x.w * w3;
    }
  }
#pragma unroll
  for (int mi = 0; mi < 32; ++mi) {
    const int m = m0 + mi, t = m >> 7, bb = m & 127;
    keysB[((size_t)bb * TIN + t) * H + k] = f2bf(acc[mi]);
  }
}

__global__ __launch_bounds__(256) void k_memB(const float* __restrict__ mem,
                                              unsigned short* __restrict__ memB) {
  const int m = blockIdx.x, t = m >> 7, bb = m & 127;
  memB[((size_t)bb * TIN + t) * H + threadIdx.x] = f2bf(mem[(size_t)m * H + threadIdx.x]);
}

// pack Wq[256][256] -> bf16 [(k>>3)*256 + c]*8 + (k&7)
__global__ __launch_bounds__(256) void k_packWq(const float* __restrict__ W,
                                                unsigned short* __restrict__ Wp) {
  const int idx = blockIdx.x * 256 + threadIdx.x;
  const int k = idx >> 8, c = idx & 255;
  Wp[(((size_t)(k >> 3) * 256) + c) * 8 + (k & 7)] = f2bf(W[idx]);
}

// pack GRU weight W[K][768] (cols z|r|c) into row-interleaved bf16:
// dst[(rowOff+k)*1024 + (j>>1)*8 + (j&1)*4 + g]; slots 3,7 are pad.
__global__ __launch_bounds__(256) void k_packG(const float* __restrict__ W,
                                               unsigned short* __restrict__ dst,
                                               int K, int rowOff) {
  const int idx = blockIdx.x * 256 + threadIdx.x;
  if (idx >= K * 768) return;
  const int k = idx / 768, c = idx - k * 768;
  const int g = c >> 8, j = c & 255;
  dst[((size_t)(rowOff + k) * 128 + (j >> 1)) * 8 + (j & 1) * 4 + g] = f2bf(W[idx]);
}

// Hoisted prenet -> preT[t][j][b] fp32
__global__ __launch_bounds__(256) void k_prenet(
    const float* __restrict__ outs, const float* __restrict__ Wp0,
    const float* __restrict__ bp0, const float* __restrict__ Wp1,
    const float* __restrict__ bp1, float* __restrict__ preT) {
  const int t = blockIdx.x >> 7, b = blockIdx.x & 127, tid = threadIdx.x;
  __shared__ float f[80];
  __shared__ float p0[256];
  __shared__ float s2[256];
  if (tid < 80)
    f[tid] = (t == 0) ? 0.f
                      : __builtin_nontemporal_load(
                            &outs[((size_t)(t * RF - 1) * B + b) * D + tid]);
  __syncthreads();
  {
    float a = bp0[tid];
#pragma unroll 8
    for (int k = 0; k < 80; ++k) a += f[k] * Wp0[k * 256 + tid];
    p0[tid] = fmaxf(a, 0.f);
  }
  __syncthreads();
  {
    const int c = tid & 127, kh = tid >> 7;
    float a = 0.f;
#pragma unroll 8
    for (int k = kh * 128; k < kh * 128 + 128; ++k) a += p0[k] * Wp1[k * 128 + c];
    s2[kh * 128 + c] = a;
  }
  __syncthreads();
  if (tid < 128)
    preT[((size_t)t * PP + tid) * B + b] = fmaxf(bp1[tid] + s2[tid] + s2[128 + tid], 0.f);
}

// ---------------------------------------------------------------------------
// GRU body: rel in [0,256) -> (jg2 = rel>>1 owns j {2jg2,2jg2+1}, bh = rel&1).
__device__ void gru_body(const unsigned short* __restrict__ wp, int K1, int K2,
                         int KH, const float* __restrict__ xT1,
                         const float* __restrict__ xT2,
                         const float* __restrict__ hT_old,
                         const float* __restrict__ b3, float* __restrict__ hT_new,
                         const float* __restrict__ resInT,
                         float* __restrict__ resOutT, int rel, float* smem) {
  const int tid = threadIdx.x;
  float* part = smem;            // 16*512
  float* red = smem + 8192;      // 512
  const int jg2 = rel >> 1, bh = rel & 1;
  const int lane = tid & 63, wv = tid >> 6;
  const int b = bh * 64 + lane;

  const uint4* wp4 = reinterpret_cast<const uint4*>(wp);
  const int K12 = K1 + K2, KT = K12 + KH;
  const int KS = KT >> 4;
  const int k0 = wv * KS, k1 = k0 + KS;

  float az0 = 0, ar0 = 0, acx0 = 0, ach0 = 0;
  float az1 = 0, ar1 = 0, acx1 = 0, ach1 = 0;
  float f0, f1;

  const int e1 = (k1 < K1) ? k1 : K1;
#pragma unroll 4
  for (int k = k0; k < e1; ++k) {
    const uint4 w = wp4[(size_t)k * 128 + jg2];
    const float x = xT1[k * B + b];
    bf2x(w.x, f0, f1); az0 += f0 * x; ar0 += f1 * x;
    bf2x(w.y, f0, f1); acx0 += f0 * x;
    bf2x(w.z, f0, f1); az1 += f0 * x; ar1 += f1 * x;
    bf2x(w.w, f0, f1); acx1 += f0 * x;
  }
  const int s2 = (k0 > K1) ? k0 : K1, e2 = (k1 < K12) ? k1 : K12;
#pragma unroll 4
  for (int k = s2; k < e2; ++k) {
    const uint4 w = wp4[(size_t)k * 128 + jg2];
    const float x = xT2[(k - K1) * B + b];
    bf2x(w.x, f0, f1); az0 += f0 * x; ar0 += f1 * x;
    bf2x(w.y, f0, f1); acx0 += f0 * x;
    bf2x(w.z, f0, f1); az1 += f0 * x; ar1 += f1 * x;
    bf2x(w.w, f0, f1); acx1 += f0 * x;
  }
  const int s3 = (k0 > K12) ? k0 : K12;
#pragma unroll 4
  for (int k = s3; k < k1; ++k) {
    const uint4 w = wp4[(size_t)k * 128 + jg2];
    const float x = hT_old[(k - K12) * B + b];
    bf2x(w.x, f0, f1); az0 += f0 * x; ar0 += f1 * x;
    bf2x(w.y, f0, f1); ach0 += f0 * x;
    bf2x(w.z, f0, f1); az1 += f0 * x; ar1 += f1 * x;
    bf2x(w.w, f0, f1); ach1 += f0 * x;
  }

  float* pw = part + wv * 512;
  pw[0 * 64 + lane] = az0;  pw[1 * 64 + lane] = ar0;
  pw[2 * 64 + lane] = acx0; pw[3 * 64 + lane] = ach0;
  pw[4 * 64 + lane] = az1;  pw[5 * 64 + lane] = ar1;
  pw[6 * 64 + lane] = acx1; pw[7 * 64 + lane] = ach1;
  __syncthreads();
  if (tid < 512) {
    float s = 0.f;
#pragma unroll
    for (int w = 0; w < 16; ++w) s += part[w * 512 + tid];
    red[tid] = s;
  }
  __syncthreads();
  if (tid < 128) {
    const int jl = tid >> 6, ln = tid & 63;
    const int j = jg2 * 2 + jl;
    const int bb = bh * 64 + ln;
    const float az = red[(jl * 4 + 0) * 64 + ln];
    const float ar = red[(jl * 4 + 1) * 64 + ln];
    const float acx = red[(jl * 4 + 2) * 64 + ln];
    const float ach = red[(jl * 4 + 3) * 64 + ln];
    const float z = sigm(az + b3[j]);
    const float r = sigm(ar + b3[H + j]);
    const float c = tanh_(acx + r * ach + b3[2 * H + j]);
    const float hold = hT_old[j * B + bb];
    const float hn = (1.f - z) * hold + z * c;
    hT_new[j * B + bb] = hn;
    if (resOutT) resOutT[j * B + bb] = resInT[j * B + bb] + hn;
  }
}

// dense for step s, batch row b: res1T -> 5 output frames
__device__ void dense_body(int s, int b, const float* __restrict__ res1T,
                           const float* __restrict__ Wo,
                           const float* __restrict__ bo, float* __restrict__ dout,
                           float* smem) {
  const int tid = threadIdx.x;
  float* red = smem;             // 256
  float* part = smem + 512;      // 1024
  if (tid < 256) red[tid] = res1T[tid * B + b];
  __syncthreads();
  {
    const int ks = tid >> 7, c = tid & 127;
    float a = 0.f;
    if (c < D) {
#pragma unroll 8
      for (int k = ks * 32; k < ks * 32 + 32; ++k) a += red[k] * Wo[k * D + c];
    }
    part[ks * 128 + c] = a;
  }
  __syncthreads();
  if (tid < D) {
    float dv = bo[tid];
#pragma unroll
    for (int ks = 0; ks < 8; ++ks) dv += part[ks * 128 + tid];
    const size_t base = (size_t)s * RF * (B * D) + (size_t)b * D + tid;
#pragma unroll
    for (int i = 0; i < RF; ++i)
      __builtin_nontemporal_store(dv, &dout[base + (size_t)i * (B * D)]);
  }
}

// attention body for (t, b): qW + e-pass + softmax + alpha + context
__device__ void attn_body(int t, int b, const float* __restrict__ qT,
                          const unsigned short* __restrict__ wqB,
                          const float* __restrict__ v_att,
                          const unsigned short* __restrict__ keysB,
                          const unsigned short* __restrict__ memB,
                          float* __restrict__ ctxT, float* __restrict__ alpha,
                          float* smem) {
  const int tid = threadIdx.x;
  const int lane = tid & 63, wv = tid >> 6;
  float* hA = smem;              // 256
  float* qk_p = smem + 256;      // 288
  float* v_p = smem + 544;       // 288
  float* scr = smem + 832;       // 8192
  float* ep = smem + 9024;       // 512
  float* r16 = smem + 9536;      // 16
  float* bc = smem + 9552;       // 2

  if (tid < 256) {
    hA[tid] = qT[tid * B + b];
    v_p[(tid >> 4) * 18 + (tid & 15)] = v_att[tid];
  }
  __syncthreads();
  const float4* hA4 = reinterpret_cast<const float4*>(hA);
  const uint4* wQ = reinterpret_cast<const uint4*>(wqB);

  {  // qW
    const int c = tid & 255, ks = tid >> 8;
    float a = 0.f;
#pragma unroll
    for (int q = 0; q < 8; ++q) {
      const int kg = ks * 8 + q;
      a += dot8(wQ[(size_t)kg * 256 + c], hA4[kg * 2], hA4[kg * 2 + 1]);
    }
    scr[ks * 256 + c] = a;
  }
  __syncthreads();
  if (tid < 256)
    qk_p[(tid >> 4) * 18 + (tid & 15)] =
        scr[tid] + scr[256 + tid] + scr[512 + tid] + scr[768 + tid];
  __syncthreads();

  {  // e-pass
    const int l16 = tid & 15, g = tid >> 4;
    float qg[16], vg[16];
#pragma unroll
    for (int i = 0; i < 16; ++i) {
      qg[i] = qk_p[l16 * 18 + i];
      vg[i] = v_p[l16 * 18 + i];
    }
    const uint4* kB = reinterpret_cast<const uint4*>(keysB + (size_t)b * TIN * H);
#pragma unroll
    for (int p = 0; p < 4; ++p) {
      const int t1 = g + p * 128, t2 = t1 + 64;
      const uint4 a0 = kB[(size_t)t1 * 32 + l16 * 2], a1 = kB[(size_t)t1 * 32 + l16 * 2 + 1];
      const uint4 b0 = kB[(size_t)t2 * 32 + l16 * 2], b1 = kB[(size_t)t2 * 32 + l16 * 2 + 1];
      float ka[16], kb2[16];
      unpack8(a0, ka); unpack8(a1, ka + 8);
      unpack8(b0, kb2); unpack8(b1, kb2 + 8);
      float s1 = 0.f, s2 = 0.f;
#pragma unroll
      for (int i = 0; i < 16; ++i) {
        s1 += vg[i] * tanh_(ka[i] + qg[i]);
        s2 += vg[i] * tanh_(kb2[i] + qg[i]);
      }
#pragma unroll
      for (int m = 1; m < 16; m <<= 1) { s1 += __shfl_xor(s1, m, 16); s2 += __shfl_xor(s2, m, 16); }
      if (l16 == 0) { ep[t1] = s1; ep[t2] = s2; }
    }
  }
  __syncthreads();

  // softmax over 512
  float ev = -1e30f, pv = 0.f;
  if (tid < TIN) {
    ev = ep[tid];
    float mx = ev;
#pragma unroll
    for (int m = 1; m < 64; m <<= 1) mx = fmaxf(mx, __shfl_xor(mx, m));
    if (lane == 0) r16[wv] = mx;
  }
  __syncthreads();
  if (tid == 0) {
    float g = r16[0];
#pragma unroll
    for (int w = 1; w < 8; ++w) g = fmaxf(g, r16[w]);
    bc[0] = g;
  }
  __syncthreads();
  const float M = bc[0];
  if (tid < TIN) {
    pv = __expf(ev - M);
    ep[tid] = pv;
    float s = pv;
#pragma unroll
    for (int m = 1; m < 64; m <<= 1) s += __shfl_xor(s, m);
    if (lane == 0) r16[wv] = s;
  }
  __syncthreads();
  if (tid == 0) {
    float s = 0.f;
#pragma unroll
    for (int w = 0; w < 8; ++w) s += r16[w];
    bc[1] = 1.f / s;
  }
  __syncthreads();
  const float inv = bc[1];
  if (tid < TIN)
    __builtin_nontemporal_store(pv * inv, &alpha[((size_t)t * B + b) * TIN + tid]);

  {  // context
    const int kq8 = tid & 31, ts = tid >> 5;
    float a[8] = {0.f, 0.f, 0.f, 0.f, 0.f, 0.f, 0.f, 0.f};
    const uint4* mB = reinterpret_cast<const uint4*>(memB + (size_t)b * TIN * H);
#pragma unroll 4
    for (int i = 0; i < 16; ++i) {
      const int tt = ts * 16 + i;
      const float p = ep[tt];
      float mv[8];
      unpack8(mB[(size_t)tt * 32 + kq8], mv);
#pragma unroll
      for (int j = 0; j < 8; ++j) a[j] += p * mv[j];
    }
    float4* s4 = reinterpret_cast<float4*>(scr + ts * 256 + kq8 * 8);
    s4[0] = make_float4(a[0], a[1], a[2], a[3]);
    s4[1] = make_float4(a[4], a[5], a[6], a[7]);
  }
  __syncthreads();
  if (tid < 256) {
    float s = 0.f;
#pragma unroll
    for (int ts2 = 0; ts2 < 32; ++ts2) s += scr[ts2 * 256 + tid];
    ctxT[tid * B + b] = inv * s;
  }
}

// ---------------------------------------------------------------------------
// 5-deep pipelined step: one dispatch i runs attn(i-1) [blocks 0..127, first
// so they start in scheduling round 1], attGRU(i) [128..383], d0(i-2)
// [384..639], d1(i-3) [640..895], dense(i-4) [896..1023]. Ring-4 buffers.
__global__ __launch_bounds__(1024) void k_pipe(
    int i, const unsigned short* __restrict__ wgA,
    const unsigned short* __restrict__ wg0, const unsigned short* __restrict__ wg1,
    const unsigned short* __restrict__ wqB, const float* __restrict__ v_att,
    const float* __restrict__ b_att, const float* __restrict__ b_d0,
    const float* __restrict__ b_d1, const unsigned short* __restrict__ keysB,
    const unsigned short* __restrict__ memB, const float* __restrict__ preT,
    float* __restrict__ qr, float* __restrict__ ctxr, float* __restrict__ hd0r,
    float* __restrict__ hd1r, float* __restrict__ res0r, float* __restrict__ res1r,
    const float* __restrict__ Wo, const float* __restrict__ bo,
    float* __restrict__ dout, float* __restrict__ alpha) {
  __shared__ alignas(16) float smem[9600];
  const int blk = blockIdx.x;
  if (blk < 128) {                      // attn(t = i-1)
    const int t = i - 1;
    if (t >= 0 && t < RSTEPS)
      attn_body(t, blk, qr + (t & 3) * HB, wqB, v_att, keysB, memB,
                ctxr + (t & 3) * HB, alpha, smem);
  } else if (blk < 384) {               // attGRU(t = i)
    const int t = i;
    if (t < RSTEPS)
      gru_body(wgA, PP, 0, H, preT + (size_t)t * PP * B, nullptr,
               qr + ((t + 3) & 3) * HB, b_att, qr + (t & 3) * HB, nullptr,
               nullptr, blk - 128, smem);
  } else if (blk < 640) {               // d0(t = i-2)
    const int t = i - 2;
    if (t >= 0 && t < RSTEPS)
      gru_body(wg0, H, H, H, qr + (t & 3) * HB, ctxr + (t & 3) * HB,
               hd0r + ((t + 3) & 3) * HB, b_d0, hd0r + (t & 3) * HB,
               qr + (t & 3) * HB, res0r + (t & 3) * HB, blk - 384, smem);
  } else if (blk < 896) {               // d1(t = i-3)
    const int t = i - 3;
    if (t >= 0 && t < RSTEPS)
      gru_body(wg1, H, 0, H, res0r + (t & 3) * HB, nullptr,
               hd1r + ((t + 3) & 3) * HB, b_d1, hd1r + (t & 3) * HB,
               res0r + (t & 3) * HB, res1r + (t & 3) * HB, blk - 640, smem);
  } else {                              // dense(t = i-4)
    const int t = i - 4;
    if (t >= 0 && t < RSTEPS)
      dense_body(t, blk - 896, res1r + (t & 3) * HB, Wo, bo, dout, smem);
  }
}

// ---------------------------------------------------------------------------
extern "C" void kernel_launch(void* const* d_in, const int* in_sizes, int n_in,
                              void* d_out, int out_size, void* d_ws,
                              size_t ws_size, hipStream_t stream) {
  const float* outs   = (const float*)d_in[0];
  const float* memory = (const float*)d_in[1];
  const float* Wp0    = (const float*)d_in[2];
  const float* bp0    = (const float*)d_in[3];
  const float* Wp1    = (const float*)d_in[4];
  const float* bp1    = (const float*)d_in[5];
  const float* Wx_att = (const float*)d_in[6];
  const float* Wh_att = (const float*)d_in[7];
  const float* b_att  = (const float*)d_in[8];
  const float* Wq     = (const float*)d_in[9];
  const float* Wm     = (const float*)d_in[10];
  const float* v_att  = (const float*)d_in[11];
  const float* Wx_d0  = (const float*)d_in[12];
  const float* Wh_d0  = (const float*)d_in[13];
  const float* b_d0   = (const float*)d_in[14];
  const float* Wx_d1  = (const float*)d_in[15];
  const float* Wh_d1  = (const float*)d_in[16];
  const float* b_d1   = (const float*)d_in[17];
  const float* Wo     = (const float*)d_in[18];
  const float* bo     = (const float*)d_in[19];
  float* dout = (float*)d_out;
  float* wsf  = (float*)d_ws;

  size_t off = 0;  // in floats
  unsigned short* keysB = (unsigned short*)(wsf + off); off += (size_t)TIN * B * H / 2;
  unsigned short* memB  = (unsigned short*)(wsf + off); off += (size_t)TIN * B * H / 2;
  unsigned short* wqB   = (unsigned short*)(wsf + off); off += (size_t)256 * 256 / 2;
  unsigned short* wgA   = (unsigned short*)(wsf + off); off += (size_t)384 * 1024 / 2;
  unsigned short* wg0   = (unsigned short*)(wsf + off); off += (size_t)768 * 1024 / 2;
  unsigned short* wg1   = (unsigned short*)(wsf + off); off += (size_t)512 * 1024 / 2;
  float* preT  = wsf + off; off += (size_t)RSTEPS * PP * B;
  float* qr    = wsf + off; off += (size_t)4 * HB;
  float* ctxr  = wsf + off; off += (size_t)4 * HB;
  float* hd0r  = wsf + off; off += (size_t)4 * HB;
  float* hd1r  = wsf + off; off += (size_t)4 * HB;
  float* res0r = wsf + off; off += (size_t)4 * HB;
  float* res1r = wsf + off; off += (size_t)4 * HB;

  // zero ring slots read at the pipeline head: state(-1) lives in slot 3
  hipMemsetAsync(qr + 3 * HB, 0, (size_t)HB * sizeof(float), stream);
  hipMemsetAsync(hd0r + 3 * HB, 0, (size_t)HB * sizeof(float), stream);
  hipMemsetAsync(hd1r + 3 * HB, 0, (size_t)HB * sizeof(float), stream);

  k_keys<<<(TIN * B) / 32, 256, 0, stream>>>(memory, Wm, keysB);
  k_memB<<<TIN * B, 256, 0, stream>>>(memory, memB);
  k_prenet<<<RSTEPS * B, 256, 0, stream>>>(outs, Wp0, bp0, Wp1, bp1, preT);
  k_packWq<<<256, 256, 0, stream>>>(Wq, wqB);
  k_packG<<<(128 * 768 + 255) / 256, 256, 0, stream>>>(Wx_att, wgA, 128, 0);
  k_packG<<<(256 * 768 + 255) / 256, 256, 0, stream>>>(Wh_att, wgA, 256, 128);
  k_packG<<<(512 * 768 + 255) / 256, 256, 0, stream>>>(Wx_d0, wg0, 512, 0);
  k_packG<<<(256 * 768 + 255) / 256, 256, 0, stream>>>(Wh_d0, wg0, 256, 512);
  k_packG<<<(256 * 768 + 255) / 256, 256, 0, stream>>>(Wx_d1, wg1, 256, 0);
  k_packG<<<(256 * 768 + 255) / 256, 256, 0, stream>>>(Wh_d1, wg1, 256, 256);

  float* alpha = dout + (size_t)1000 * B * D;

  for (int i = 0; i < RSTEPS + 4; ++i) {
    k_pipe<<<1024, 1024, 0, stream>>>(i, wgA, wg0, wg1, wqB, v_att, b_att,
                                      b_d0, b_d1, keysB, memB, preT, qr, ctxr,
                                      hd0r, hd1r, res0r, res1r, Wo, bo, dout,
                                      alpha);
  }
}

// Round 13
// 7791.570 us; speedup vs baseline: 12.5149x; 1.1368x over previous
//
#include <hip/hip_runtime.h>

namespace {
constexpr int B = 128;      // batch
constexpr int D = 80;       // mel dim
constexpr int H = 256;      // hidden
constexpr int PP = 128;     // prenet out
constexpr int TIN = 512;    // encoder steps
constexpr int RSTEPS = 200; // reduced steps
constexpr int RF = 5;       // reduction factor
constexpr int HB = H * B;   // ring slot stride
}

__device__ __forceinline__ float sigm(float x) { return 1.f / (1.f + __expf(-x)); }
__device__ __forceinline__ float tanh_(float x) { return 1.f - 2.f / (__expf(2.f * x) + 1.f); }
__device__ __forceinline__ unsigned short f2bf(float f) {  // RNE
  unsigned int u = __float_as_uint(f);
  u += 0x7fffu + ((u >> 16) & 1u);
  return (unsigned short)(u >> 16);
}
__device__ __forceinline__ void bf2x(unsigned int w, float& f0, float& f1) {
  f0 = __uint_as_float(w << 16);
  f1 = __uint_as_float(w & 0xffff0000u);
}
__device__ __forceinline__ void unpack8(uint4 w, float* f) {
  bf2x(w.x, f[0], f[1]); bf2x(w.y, f[2], f[3]);
  bf2x(w.z, f[4], f[5]); bf2x(w.w, f[6], f[7]);
}
__device__ __forceinline__ float dot8(uint4 w, float4 x0, float4 x1) {
  float f0, f1, a;
  bf2x(w.x, f0, f1); a  = f0 * x0.x + f1 * x0.y;
  bf2x(w.y, f0, f1); a += f0 * x0.z + f1 * x0.w;
  bf2x(w.z, f0, f1); a += f0 * x1.x + f1 * x1.y;
  bf2x(w.w, f0, f1); a += f0 * x1.z + f1 * x1.w;
  return a;
}

// ---------------------------------------------------------------------------
__global__ __launch_bounds__(256) void k_keys(const float* __restrict__ mem,
                                              const float* __restrict__ Wm,
                                              unsigned short* __restrict__ keysB) {
  const int k = threadIdx.x;
  const int m0 = blockIdx.x * 32;
  const float* xb = mem + (size_t)m0 * H;
  float acc[32];
#pragma unroll
  for (int i = 0; i < 32; ++i) acc[i] = 0.f;
  for (int h = 0; h < H; h += 4) {
    const float w0 = Wm[(h + 0) * H + k];
    const float w1 = Wm[(h + 1) * H + k];
    const float w2 = Wm[(h + 2) * H + k];
    const float w3 = Wm[(h + 3) * H + k];
#pragma unroll
    for (int mi = 0; mi < 32; ++mi) {
      const float4 x = *reinterpret_cast<const float4*>(xb + (size_t)mi * H + h);
      acc[mi] += x.x * w0 + x.y * w1 + x.z * w2 + x.w * w3;
    }
  }
#pragma unroll
  for (int mi = 0; mi < 32; ++mi) {
    const int m = m0 + mi, t = m >> 7, bb = m & 127;
    keysB[((size_t)bb * TIN + t) * H + k] = f2bf(acc[mi]);
  }
}

__global__ __launch_bounds__(256) void k_memB(const float* __restrict__ mem,
                                              unsigned short* __restrict__ memB) {
  const int m = blockIdx.x, t = m >> 7, bb = m & 127;
  memB[((size_t)bb * TIN + t) * H + threadIdx.x] = f2bf(mem[(size_t)m * H + threadIdx.x]);
}

__global__ __launch_bounds__(256) void k_packWq(const float* __restrict__ W,
                                                unsigned short* __restrict__ Wp) {
  const int idx = blockIdx.x * 256 + threadIdx.x;
  const int k = idx >> 8, c = idx & 255;
  Wp[(((size_t)(k >> 3) * 256) + c) * 8 + (k & 7)] = f2bf(W[idx]);
}

// pack GRU weight W[K][768] (cols z|r|c) -> row-interleaved bf16:
// dst[(rowOff+k)*1024 + (j>>1)*8 + (j&1)*4 + g]; slots 3,7 pad.
__global__ __launch_bounds__(256) void k_packG(const float* __restrict__ W,
                                               unsigned short* __restrict__ dst,
                                               int K, int rowOff) {
  const int idx = blockIdx.x * 256 + threadIdx.x;
  if (idx >= K * 768) return;
  const int k = idx / 768, c = idx - k * 768;
  const int g = c >> 8, j = c & 255;
  dst[((size_t)(rowOff + k) * 128 + (j >> 1)) * 8 + (j & 1) * 4 + g] = f2bf(W[idx]);
}

// Hoisted prenet -> preT[t][j][b] fp32
__global__ __launch_bounds__(256) void k_prenet(
    const float* __restrict__ outs, const float* __restrict__ Wp0,
    const float* __restrict__ bp0, const float* __restrict__ Wp1,
    const float* __restrict__ bp1, float* __restrict__ preT) {
  const int t = blockIdx.x >> 7, b = blockIdx.x & 127, tid = threadIdx.x;
  __shared__ float f[80];
  __shared__ float p0[256];
  __shared__ float s2[256];
  if (tid < 80)
    f[tid] = (t == 0) ? 0.f
                      : __builtin_nontemporal_load(
                            &outs[((size_t)(t * RF - 1) * B + b) * D + tid]);
  __syncthreads();
  {
    float a = bp0[tid];
#pragma unroll 8
    for (int k = 0; k < 80; ++k) a += f[k] * Wp0[k * 256 + tid];
    p0[tid] = fmaxf(a, 0.f);
  }
  __syncthreads();
  {
    const int c = tid & 127, kh = tid >> 7;
    float a = 0.f;
#pragma unroll 8
    for (int k = kh * 128; k < kh * 128 + 128; ++k) a += p0[k] * Wp1[k * 128 + c];
    s2[kh * 128 + c] = a;
  }
  __syncthreads();
  if (tid < 128)
    preT[((size_t)t * PP + tid) * B + b] = fmaxf(bp1[tid] + s2[tid] + s2[128 + tid], 0.f);
}

// ---------------------------------------------------------------------------
// 8-wave GRU body (512 threads): rel -> (jg2 = rel>>1, bh = rel&1).
// If pctx0 != nullptr, x2[k][b] is reconstructed from attention partials:
// x2 = c0*pctx0[k*B+b] + c1*pctx0[(256+k)*B+b], factors from msp.
__device__ void gru_body(const unsigned short* __restrict__ wp, int K1, int K2,
                         int KH, const float* __restrict__ xT1,
                         const float* __restrict__ xT2,
                         const float* __restrict__ pctx0,
                         const float* __restrict__ msp,
                         const float* __restrict__ hT_old,
                         const float* __restrict__ b3, float* __restrict__ hT_new,
                         const float* __restrict__ resInT,
                         float* __restrict__ resOutT, int rel, float* smem) {
  const int tid = threadIdx.x;
  float* part = smem;            // 8*512
  float* red = smem + 4096;     // 512
  const int jg2 = rel >> 1, bh = rel & 1;
  const int lane = tid & 63, wv = tid >> 6;
  const int b = bh * 64 + lane;

  float c0 = 0.f, c1 = 0.f;
  if (pctx0) {
    const float m0 = msp[b], s0 = msp[B + b];
    const float m1 = msp[2 * B + b], s1 = msp[3 * B + b];
    const float M = fmaxf(m0, m1);
    const float f0 = __expf(m0 - M), f1 = __expf(m1 - M);
    const float inv = 1.f / (s0 * f0 + s1 * f1);
    c0 = f0 * inv; c1 = f1 * inv;
  }

  const uint4* wp4 = reinterpret_cast<const uint4*>(wp);
  const int K12 = K1 + K2, KT = K12 + KH;
  const int KS = KT >> 3;
  const int k0 = wv * KS, k1 = k0 + KS;

  float az0 = 0, ar0 = 0, acx0 = 0, ach0 = 0;
  float az1 = 0, ar1 = 0, acx1 = 0, ach1 = 0;
  float f0, f1;

  const int e1 = (k1 < K1) ? k1 : K1;
#pragma unroll 4
  for (int k = k0; k < e1; ++k) {
    const uint4 w = wp4[(size_t)k * 128 + jg2];
    const float x = xT1[k * B + b];
    bf2x(w.x, f0, f1); az0 += f0 * x; ar0 += f1 * x;
    bf2x(w.y, f0, f1); acx0 += f0 * x;
    bf2x(w.z, f0, f1); az1 += f0 * x; ar1 += f1 * x;
    bf2x(w.w, f0, f1); acx1 += f0 * x;
  }
  const int s2 = (k0 > K1) ? k0 : K1, e2 = (k1 < K12) ? k1 : K12;
#pragma unroll 2
  for (int k = s2; k < e2; ++k) {
    const int kk = k - K1;
    const float x = pctx0 ? (c0 * pctx0[kk * B + b] + c1 * pctx0[(256 + kk) * B + b])
                          : xT2[kk * B + b];
    const uint4 w = wp4[(size_t)k * 128 + jg2];
    bf2x(w.x, f0, f1); az0 += f0 * x; ar0 += f1 * x;
    bf2x(w.y, f0, f1); acx0 += f0 * x;
    bf2x(w.z, f0, f1); az1 += f0 * x; ar1 += f1 * x;
    bf2x(w.w, f0, f1); acx1 += f0 * x;
  }
  const int s3 = (k0 > K12) ? k0 : K12;
#pragma unroll 4
  for (int k = s3; k < k1; ++k) {
    const uint4 w = wp4[(size_t)k * 128 + jg2];
    const float x = hT_old[(k - K12) * B + b];
    bf2x(w.x, f0, f1); az0 += f0 * x; ar0 += f1 * x;
    bf2x(w.y, f0, f1); ach0 += f0 * x;
    bf2x(w.z, f0, f1); az1 += f0 * x; ar1 += f1 * x;
    bf2x(w.w, f0, f1); ach1 += f0 * x;
  }

  float* pw = part + wv * 512;
  pw[0 * 64 + lane] = az0;  pw[1 * 64 + lane] = ar0;
  pw[2 * 64 + lane] = acx0; pw[3 * 64 + lane] = ach0;
  pw[4 * 64 + lane] = az1;  pw[5 * 64 + lane] = ar1;
  pw[6 * 64 + lane] = acx1; pw[7 * 64 + lane] = ach1;
  __syncthreads();
  {
    float s = 0.f;
#pragma unroll
    for (int w = 0; w < 8; ++w) s += part[w * 512 + tid];
    red[tid] = s;
  }
  __syncthreads();
  if (tid < 128) {
    const int jl = tid >> 6, ln = tid & 63;
    const int j = jg2 * 2 + jl;
    const int bb = bh * 64 + ln;
    const float az = red[(jl * 4 + 0) * 64 + ln];
    const float ar = red[(jl * 4 + 1) * 64 + ln];
    const float acx = red[(jl * 4 + 2) * 64 + ln];
    const float ach = red[(jl * 4 + 3) * 64 + ln];
    const float z = sigm(az + b3[j]);
    const float r = sigm(ar + b3[H + j]);
    const float c = tanh_(acx + r * ach + b3[2 * H + j]);
    const float hold = hT_old[j * B + bb];
    const float hn = (1.f - z) * hold + z * c;
    hT_new[j * B + bb] = hn;
    if (resOutT) resOutT[j * B + bb] = resInT[j * B + bb] + hn;
  }
}

// dense (512 threads) + alpha finalize for step s, batch row b
__device__ void dense_body(int s, int b, const float* __restrict__ res1T,
                           const float* __restrict__ Wo,
                           const float* __restrict__ bo, float* __restrict__ dout,
                           const float* __restrict__ pvalsS,
                           const float* __restrict__ msS,
                           float* __restrict__ alpha, float* smem) {
  const int tid = threadIdx.x;
  float* red = smem;             // 256
  float* part = smem + 256;      // 512
  if (tid < 256) red[tid] = res1T[tid * B + b];
  __syncthreads();
  {
    const int ks = tid >> 7, c = tid & 127;
    float a = 0.f;
    if (c < D) {
#pragma unroll 8
      for (int k = ks * 64; k < ks * 64 + 64; ++k) a += red[k] * Wo[k * D + c];
    }
    part[ks * 128 + c] = a;
  }
  __syncthreads();
  if (tid < D) {
    float dv = bo[tid];
#pragma unroll
    for (int ks = 0; ks < 4; ++ks) dv += part[ks * 128 + tid];
    const size_t base = (size_t)s * RF * (B * D) + (size_t)b * D + tid;
#pragma unroll
    for (int i = 0; i < RF; ++i)
      __builtin_nontemporal_store(dv, &dout[base + (size_t)i * (B * D)]);
  }
  // alpha = pvals * combine
  const float m0 = msS[b], s0 = msS[B + b], m1 = msS[2 * B + b], s1 = msS[3 * B + b];
  const float M = fmaxf(m0, m1);
  const float f0 = __expf(m0 - M), f1 = __expf(m1 - M);
  const float inv = 1.f / (s0 * f0 + s1 * f1);
  const float cc = (tid < 256) ? f0 * inv : f1 * inv;
  __builtin_nontemporal_store(pvalsS[(size_t)b * TIN + tid] * cc,
                              &alpha[((size_t)s * B + b) * TIN + tid]);
}

// attention half (512 threads): qW + e over 256 t's + partial softmax + pctx
__device__ void attn_half_body(int b, int half, const float* __restrict__ qT,
                               const unsigned short* __restrict__ wqB,
                               const float* __restrict__ v_att,
                               const unsigned short* __restrict__ keysB,
                               const unsigned short* __restrict__ memB,
                               float* __restrict__ pvalsS, float* __restrict__ pctxS,
                               float* __restrict__ msS, float* smem) {
  const int tid = threadIdx.x;
  const int lane = tid & 63, wv = tid >> 6;
  const int t0 = half * 256;
  float* hA = smem;              // 256
  float* qk_p = smem + 256;      // 288
  float* v_p = smem + 544;       // 288
  float* scr = smem + 832;       // 4096
  float* ep = smem + 4928;       // 256
  float* r16 = smem + 5184;      // 16
  float* bc = smem + 5200;       // 2

  if (tid < 256) {
    hA[tid] = qT[tid * B + b];
    v_p[(tid >> 4) * 18 + (tid & 15)] = v_att[tid];
  }
  __syncthreads();
  const float4* hA4 = reinterpret_cast<const float4*>(hA);
  const uint4* wQ = reinterpret_cast<const uint4*>(wqB);

  {  // qW: 2-way split-K, 256 cols
    const int c = tid & 255, ks = tid >> 8;
    float a = 0.f;
#pragma unroll
    for (int q = 0; q < 16; ++q) {
      const int kg = ks * 16 + q;
      a += dot8(wQ[(size_t)kg * 256 + c], hA4[kg * 2], hA4[kg * 2 + 1]);
    }
    scr[ks * 256 + c] = a;
  }
  __syncthreads();
  if (tid < 256)
    qk_p[(tid >> 4) * 18 + (tid & 15)] = scr[tid] + scr[256 + tid];
  __syncthreads();

  {  // e-pass: 32 groups x 16 lanes, 8 rows each (2 in flight)
    const int l16 = tid & 15, g = tid >> 4;
    float qg[16], vg[16];
#pragma unroll
    for (int i = 0; i < 16; ++i) {
      qg[i] = qk_p[l16 * 18 + i];
      vg[i] = v_p[l16 * 18 + i];
    }
    const uint4* kB = reinterpret_cast<const uint4*>(keysB + (size_t)b * TIN * H);
#pragma unroll
    for (int p = 0; p < 4; ++p) {
      const int r1 = g + p * 64, r2 = r1 + 32;
      const uint4 a0 = kB[(size_t)(t0 + r1) * 32 + l16 * 2];
      const uint4 a1 = kB[(size_t)(t0 + r1) * 32 + l16 * 2 + 1];
      const uint4 b0 = kB[(size_t)(t0 + r2) * 32 + l16 * 2];
      const uint4 b1 = kB[(size_t)(t0 + r2) * 32 + l16 * 2 + 1];
      float ka[16], kb2[16];
      unpack8(a0, ka); unpack8(a1, ka + 8);
      unpack8(b0, kb2); unpack8(b1, kb2 + 8);
      float s1 = 0.f, s2 = 0.f;
#pragma unroll
      for (int i = 0; i < 16; ++i) {
        s1 += vg[i] * tanh_(ka[i] + qg[i]);
        s2 += vg[i] * tanh_(kb2[i] + qg[i]);
      }
#pragma unroll
      for (int m = 1; m < 16; m <<= 1) { s1 += __shfl_xor(s1, m, 16); s2 += __shfl_xor(s2, m, 16); }
      if (l16 == 0) { ep[r1] = s1; ep[r2] = s2; }
    }
  }
  __syncthreads();

  // partial softmax over 256
  float ev = -1e30f, pv = 0.f;
  if (tid < 256) {
    ev = ep[tid];
    float mx = ev;
#pragma unroll
    for (int m = 1; m < 64; m <<= 1) mx = fmaxf(mx, __shfl_xor(mx, m));
    if (lane == 0) r16[wv] = mx;
  }
  __syncthreads();
  if (tid == 0)
    bc[0] = fmaxf(fmaxf(r16[0], r16[1]), fmaxf(r16[2], r16[3]));
  __syncthreads();
  const float M = bc[0];
  if (tid < 256) {
    pv = __expf(ev - M);
    ep[tid] = pv;
    pvalsS[(size_t)b * TIN + t0 + tid] = pv;
    float s = pv;
#pragma unroll
    for (int m = 1; m < 64; m <<= 1) s += __shfl_xor(s, m);
    if (lane == 0) r16[wv] = s;
  }
  __syncthreads();
  if (tid == 0) {
    msS[half * 2 * B + b] = M;
    msS[(half * 2 + 1) * B + b] = r16[0] + r16[1] + r16[2] + r16[3];
  }

  {  // partial context (unnormalized)
    const int kq8 = tid & 31, ts = tid >> 5;  // 16 t-slices x 16 t
    float a[8] = {0.f, 0.f, 0.f, 0.f, 0.f, 0.f, 0.f, 0.f};
    const uint4* mB = reinterpret_cast<const uint4*>(memB + (size_t)b * TIN * H);
#pragma unroll 4
    for (int i = 0; i < 16; ++i) {
      const int tt = ts * 16 + i;
      const float p = ep[tt];
      float mv[8];
      unpack8(mB[(size_t)(t0 + tt) * 32 + kq8], mv);
#pragma unroll
      for (int j = 0; j < 8; ++j) a[j] += p * mv[j];
    }
    float4* s4 = reinterpret_cast<float4*>(scr + ts * 256 + kq8 * 8);
    s4[0] = make_float4(a[0], a[1], a[2], a[3]);
    s4[1] = make_float4(a[4], a[5], a[6], a[7]);
  }
  __syncthreads();
  if (tid < 256) {
    float s = 0.f;
#pragma unroll
    for (int ts2 = 0; ts2 < 16; ++ts2) s += scr[ts2 * 256 + tid];
    pctxS[(size_t)(half * 256 + tid) * B + b] = s;
  }
}

// ---------------------------------------------------------------------------
// 5-deep pipeline, 512-thread blocks: attn_half(i-1) [0..255], attGRU(i)
// [256..511], d0(i-2) [512..767], d1(i-3) [768..1023], dense+alpha(i-4)
// [1024..1151]. Ring-4 buffers.
__global__ __launch_bounds__(512, 8) void k_pipe(
    int i, const unsigned short* __restrict__ wgA,
    const unsigned short* __restrict__ wg0, const unsigned short* __restrict__ wg1,
    const unsigned short* __restrict__ wqB, const float* __restrict__ v_att,
    const float* __restrict__ b_att, const float* __restrict__ b_d0,
    const float* __restrict__ b_d1, const unsigned short* __restrict__ keysB,
    const unsigned short* __restrict__ memB, const float* __restrict__ preT,
    float* __restrict__ qr, float* __restrict__ hd0r, float* __restrict__ hd1r,
    float* __restrict__ res0r, float* __restrict__ res1r,
    float* __restrict__ pvals, float* __restrict__ pctx, float* __restrict__ ms,
    const float* __restrict__ Wo, const float* __restrict__ bo,
    float* __restrict__ dout, float* __restrict__ alpha) {
  __shared__ alignas(16) float smem[5248];
  const int blk = blockIdx.x;
  if (blk < 256) {                      // attn_half(t = i-1)
    const int t = i - 1;
    if (t >= 0 && t < RSTEPS) {
      const int sl = t & 3;
      attn_half_body(blk >> 1, blk & 1, qr + (size_t)sl * HB, wqB, v_att, keysB,
                     memB, pvals + (size_t)sl * B * TIN,
                     pctx + (size_t)sl * 2 * HB, ms + (size_t)sl * 4 * B, smem);
    }
  } else if (blk < 512) {               // attGRU(t = i)
    const int t = i;
    if (t < RSTEPS)
      gru_body(wgA, PP, 0, H, preT + (size_t)t * PP * B, nullptr, nullptr,
               nullptr, qr + (size_t)((t + 3) & 3) * HB, b_att,
               qr + (size_t)(t & 3) * HB, nullptr, nullptr, blk - 256, smem);
  } else if (blk < 768) {               // d0(t = i-2), ctx from partials
    const int t = i - 2;
    if (t >= 0 && t < RSTEPS) {
      const int sl = t & 3;
      gru_body(wg0, H, H, H, qr + (size_t)sl * HB, nullptr,
               pctx + (size_t)sl * 2 * HB, ms + (size_t)sl * 4 * B,
               hd0r + (size_t)((t + 3) & 3) * HB, b_d0,
               hd0r + (size_t)sl * HB, qr + (size_t)sl * HB,
               res0r + (size_t)sl * HB, blk - 512, smem);
    }
  } else if (blk < 1024) {              // d1(t = i-3)
    const int t = i - 3;
    if (t >= 0 && t < RSTEPS) {
      const int sl = t & 3;
      gru_body(wg1, H, 0, H, res0r + (size_t)sl * HB, nullptr, nullptr, nullptr,
               hd1r + (size_t)((t + 3) & 3) * HB, b_d1, hd1r + (size_t)sl * HB,
               res0r + (size_t)sl * HB, res1r + (size_t)sl * HB, blk - 768, smem);
    }
  } else {                              // dense+alpha(t = i-4)
    const int t = i - 4;
    if (t >= 0 && t < RSTEPS) {
      const int sl = t & 3;
      dense_body(t, blk - 1024, res1r + (size_t)sl * HB, Wo, bo, dout,
                 pvals + (size_t)sl * B * TIN, ms + (size_t)sl * 4 * B, alpha,
                 smem);
    }
  }
}

// ---------------------------------------------------------------------------
extern "C" void kernel_launch(void* const* d_in, const int* in_sizes, int n_in,
                              void* d_out, int out_size, void* d_ws,
                              size_t ws_size, hipStream_t stream) {
  const float* outs   = (const float*)d_in[0];
  const float* memory = (const float*)d_in[1];
  const float* Wp0    = (const float*)d_in[2];
  const float* bp0    = (const float*)d_in[3];
  const float* Wp1    = (const float*)d_in[4];
  const float* bp1    = (const float*)d_in[5];
  const float* Wx_att = (const float*)d_in[6];
  const float* Wh_att = (const float*)d_in[7];
  const float* b_att  = (const float*)d_in[8];
  const float* Wq     = (const float*)d_in[9];
  const float* Wm     = (const float*)d_in[10];
  const float* v_att  = (const float*)d_in[11];
  const float* Wx_d0  = (const float*)d_in[12];
  const float* Wh_d0  = (const float*)d_in[13];
  const float* b_d0   = (const float*)d_in[14];
  const float* Wx_d1  = (const float*)d_in[15];
  const float* Wh_d1  = (const float*)d_in[16];
  const float* b_d1   = (const float*)d_in[17];
  const float* Wo     = (const float*)d_in[18];
  const float* bo     = (const float*)d_in[19];
  float* dout = (float*)d_out;
  float* wsf  = (float*)d_ws;

  size_t off = 0;  // in floats
  unsigned short* keysB = (unsigned short*)(wsf + off); off += (size_t)TIN * B * H / 2;
  unsigned short* memB  = (unsigned short*)(wsf + off); off += (size_t)TIN * B * H / 2;
  unsigned short* wqB   = (unsigned short*)(wsf + off); off += (size_t)256 * 256 / 2;
  unsigned short* wgA   = (unsigned short*)(wsf + off); off += (size_t)384 * 1024 / 2;
  unsigned short* wg0   = (unsigned short*)(wsf + off); off += (size_t)768 * 1024 / 2;
  unsigned short* wg1   = (unsigned short*)(wsf + off); off += (size_t)512 * 1024 / 2;
  float* preT  = wsf + off; off += (size_t)RSTEPS * PP * B;
  float* qr    = wsf + off; off += (size_t)4 * HB;
  float* hd0r  = wsf + off; off += (size_t)4 * HB;
  float* hd1r  = wsf + off; off += (size_t)4 * HB;
  float* res0r = wsf + off; off += (size_t)4 * HB;
  float* res1r = wsf + off; off += (size_t)4 * HB;
  float* pvals = wsf + off; off += (size_t)4 * B * TIN;
  float* pctx  = wsf + off; off += (size_t)4 * 2 * HB;
  float* ms    = wsf + off; off += (size_t)4 * 4 * B;

  // zero ring slots read at the pipeline head: state(-1) lives in slot 3
  hipMemsetAsync(qr + 3 * HB, 0, (size_t)HB * sizeof(float), stream);
  hipMemsetAsync(hd0r + 3 * HB, 0, (size_t)HB * sizeof(float), stream);
  hipMemsetAsync(hd1r + 3 * HB, 0, (size_t)HB * sizeof(float), stream);

  k_keys<<<(TIN * B) / 32, 256, 0, stream>>>(memory, Wm, keysB);
  k_memB<<<TIN * B, 256, 0, stream>>>(memory, memB);
  k_prenet<<<RSTEPS * B, 256, 0, stream>>>(outs, Wp0, bp0, Wp1, bp1, preT);
  k_packWq<<<256, 256, 0, stream>>>(Wq, wqB);
  k_packG<<<(128 * 768 + 255) / 256, 256, 0, stream>>>(Wx_att, wgA, 128, 0);
  k_packG<<<(256 * 768 + 255) / 256, 256, 0, stream>>>(Wh_att, wgA, 256, 128);
  k_packG<<<(512 * 768 + 255) / 256, 256, 0, stream>>>(Wx_d0, wg0, 512, 0);
  k_packG<<<(256 * 768 + 255) / 256, 256, 0, stream>>>(Wh_d0, wg0, 256, 512);
  k_packG<<<(256 * 768 + 255) / 256, 256, 0, stream>>>(Wx_d1, wg1, 256, 0);
  k_packG<<<(256 * 768 + 255) / 256, 256, 0, stream>>>(Wh_d1, wg1, 256, 256);

  float* alpha = dout + (size_t)1000 * B * D;

  for (int i = 0; i < RSTEPS + 4; ++i) {
    k_pipe<<<1152, 512, 0, stream>>>(i, wgA, wg0, wg1, wqB, v_att, b_att,
                                     b_d0, b_d1, keysB, memB, preT, qr, hd0r,
                                     hd1r, res0r, res1r, pvals, pctx, ms, Wo,
                                     bo, dout, alpha);
  }
}

// Round 14
// 7502.426 us; speedup vs baseline: 12.9973x; 1.0385x over previous
//
#include <hip/hip_runtime.h>

namespace {
constexpr int B = 128;      // batch
constexpr int D = 80;       // mel dim
constexpr int H = 256;      // hidden
constexpr int PP = 128;     // prenet out
constexpr int TIN = 512;    // encoder steps
constexpr int RSTEPS = 200; // reduced steps
constexpr int RF = 5;       // reduction factor
constexpr int HB = H * B;   // ring slot stride
}

__device__ __forceinline__ float sigm(float x) { return 1.f / (1.f + __expf(-x)); }
__device__ __forceinline__ float tanh_(float x) { return 1.f - 2.f / (__expf(2.f * x) + 1.f); }
__device__ __forceinline__ unsigned short f2bf(float f) {  // RNE
  unsigned int u = __float_as_uint(f);
  u += 0x7fffu + ((u >> 16) & 1u);
  return (unsigned short)(u >> 16);
}
__device__ __forceinline__ void bf2x(unsigned int w, float& f0, float& f1) {
  f0 = __uint_as_float(w << 16);
  f1 = __uint_as_float(w & 0xffff0000u);
}
__device__ __forceinline__ void unpack8(uint4 w, float* f) {
  bf2x(w.x, f[0], f[1]); bf2x(w.y, f[2], f[3]);
  bf2x(w.z, f[4], f[5]); bf2x(w.w, f[6], f[7]);
}
__device__ __forceinline__ float dot8(uint4 w, float4 x0, float4 x1) {
  float f0, f1, a;
  bf2x(w.x, f0, f1); a  = f0 * x0.x + f1 * x0.y;
  bf2x(w.y, f0, f1); a += f0 * x0.z + f1 * x0.w;
  bf2x(w.z, f0, f1); a += f0 * x1.x + f1 * x1.y;
  bf2x(w.w, f0, f1); a += f0 * x1.z + f1 * x1.w;
  return a;
}

// ---------------------------------------------------------------------------
// Block = (b, 32-t chunk): contiguous keysB/memB stores; fused memB emit.
__global__ __launch_bounds__(256) void k_keys(const float* __restrict__ mem,
                                              const float* __restrict__ Wm,
                                              unsigned short* __restrict__ keysB,
                                              unsigned short* __restrict__ memB) {
  const int k = threadIdx.x;
  const int bb = blockIdx.x >> 4, t0 = (blockIdx.x & 15) * 32;
  const float* base = mem + (size_t)t0 * (B * H) + (size_t)bb * H;
  float acc[32];
#pragma unroll
  for (int i = 0; i < 32; ++i) acc[i] = 0.f;
  for (int h = 0; h < H; h += 4) {
    const float w0 = Wm[(h + 0) * H + k];
    const float w1 = Wm[(h + 1) * H + k];
    const float w2 = Wm[(h + 2) * H + k];
    const float w3 = Wm[(h + 3) * H + k];
#pragma unroll
    for (int ti = 0; ti < 32; ++ti) {
      const float4 x = *reinterpret_cast<const float4*>(base + (size_t)ti * (B * H) + h);
      acc[ti] += x.x * w0 + x.y * w1 + x.z * w2 + x.w * w3;
    }
  }
#pragma unroll
  for (int ti = 0; ti < 32; ++ti) {
    const size_t o = ((size_t)bb * TIN + t0 + ti) * H + k;
    keysB[o] = f2bf(acc[ti]);
    memB[o] = f2bf(base[(size_t)ti * (B * H) + k]);
  }
}

__global__ __launch_bounds__(256) void k_packWq(const float* __restrict__ W,
                                                unsigned short* __restrict__ Wp) {
  const int idx = blockIdx.x * 256 + threadIdx.x;
  const int k = idx >> 8, c = idx & 255;
  Wp[(((size_t)(k >> 3) * 256) + c) * 8 + (k & 7)] = f2bf(W[idx]);
}

// pack GRU weight W[K][768] (cols z|r|c) -> row-interleaved bf16:
// dst[(rowOff+k)*1024 + (j>>1)*8 + (j&1)*4 + g]; slots 3,7 pad.
__global__ __launch_bounds__(256) void k_packG(const float* __restrict__ W,
                                               unsigned short* __restrict__ dst,
                                               int K, int rowOff) {
  const int idx = blockIdx.x * 256 + threadIdx.x;
  if (idx >= K * 768) return;
  const int k = idx / 768, c = idx - k * 768;
  const int g = c >> 8, j = c & 255;
  dst[((size_t)(rowOff + k) * 128 + (j >> 1)) * 8 + (j & 1) * 4 + g] = f2bf(W[idx]);
}

// Hoisted prenet -> preT[t][j][b] fp32
__global__ __launch_bounds__(256) void k_prenet(
    const float* __restrict__ outs, const float* __restrict__ Wp0,
    const float* __restrict__ bp0, const float* __restrict__ Wp1,
    const float* __restrict__ bp1, float* __restrict__ preT) {
  const int t = blockIdx.x >> 7, b = blockIdx.x & 127, tid = threadIdx.x;
  __shared__ float f[80];
  __shared__ float p0[256];
  __shared__ float s2[256];
  if (tid < 80)
    f[tid] = (t == 0) ? 0.f
                      : __builtin_nontemporal_load(
                            &outs[((size_t)(t * RF - 1) * B + b) * D + tid]);
  __syncthreads();
  {
    float a = bp0[tid];
#pragma unroll 8
    for (int k = 0; k < 80; ++k) a += f[k] * Wp0[k * 256 + tid];
    p0[tid] = fmaxf(a, 0.f);
  }
  __syncthreads();
  {
    const int c = tid & 127, kh = tid >> 7;
    float a = 0.f;
#pragma unroll 8
    for (int k = kh * 128; k < kh * 128 + 128; ++k) a += p0[k] * Wp1[k * 128 + c];
    s2[kh * 128 + c] = a;
  }
  __syncthreads();
  if (tid < 128)
    preT[((size_t)t * PP + tid) * B + b] = fmaxf(bp1[tid] + s2[tid] + s2[128 + tid], 0.f);
}

// ---------------------------------------------------------------------------
// 8-wave GRU body, NJP j-pairs per block. rel -> (grp = rel>>1, bh = rel&1).
// If pctx0 != nullptr, x2 reconstructed from attention partials via msp.
template <int NJP>
__device__ void gru_body(const unsigned short* __restrict__ wp, int K1, int K2,
                         int KH, const float* __restrict__ xT1,
                         const float* __restrict__ xT2,
                         const float* __restrict__ pctx0,
                         const float* __restrict__ msp,
                         const float* __restrict__ hT_old,
                         const float* __restrict__ b3, float* __restrict__ hT_new,
                         const float* __restrict__ resInT,
                         float* __restrict__ resOutT, int rel, float* smem) {
  const int tid = threadIdx.x;
  float* part = smem;                       // 8 * NJP*512
  float* red = smem + 8 * NJP * 512;        // NJP*512
  const int grp = rel >> 1, bh = rel & 1;
  const int lane = tid & 63, wv = tid >> 6;
  const int b = bh * 64 + lane;

  float c0 = 0.f, c1 = 0.f;
  if (pctx0) {
    const float m0 = msp[b], s0 = msp[B + b];
    const float m1 = msp[2 * B + b], s1 = msp[3 * B + b];
    const float M = fmaxf(m0, m1);
    const float e0 = __expf(m0 - M), e1 = __expf(m1 - M);
    const float inv = 1.f / (s0 * e0 + s1 * e1);
    c0 = e0 * inv; c1 = e1 * inv;
  }

  const uint4* wp4 = reinterpret_cast<const uint4*>(wp);
  const int K12 = K1 + K2, KT = K12 + KH;
  const int KS = KT >> 3;
  const int k0 = wv * KS, k1 = k0 + KS;

  float acc[NJP * 8];
#pragma unroll
  for (int i = 0; i < NJP * 8; ++i) acc[i] = 0.f;
  float f0, f1;

#define UPD(wq, xv, base, CS)                                                  \
  bf2x(wq.x, f0, f1); acc[base + 0] += f0 * xv; acc[base + 1] += f1 * xv;      \
  bf2x(wq.y, f0, f1); acc[base + CS] += f0 * xv;                               \
  bf2x(wq.z, f0, f1); acc[base + 4] += f0 * xv; acc[base + 5] += f1 * xv;      \
  bf2x(wq.w, f0, f1); acc[base + 4 + CS] += f0 * xv;

  const int e1i = (k1 < K1) ? k1 : K1;
#pragma unroll 2
  for (int k = k0; k < e1i; ++k) {
    const float x = xT1[k * B + b];
#pragma unroll
    for (int p = 0; p < NJP; ++p) {
      const uint4 w = wp4[(size_t)k * 128 + grp * NJP + p];
      UPD(w, x, p * 8, 2)
    }
  }
  const int s2i = (k0 > K1) ? k0 : K1, e2i = (k1 < K12) ? k1 : K12;
#pragma unroll 2
  for (int k = s2i; k < e2i; ++k) {
    const int kk = k - K1;
    const float x = pctx0 ? (c0 * pctx0[kk * B + b] + c1 * pctx0[(256 + kk) * B + b])
                          : xT2[kk * B + b];
#pragma unroll
    for (int p = 0; p < NJP; ++p) {
      const uint4 w = wp4[(size_t)k * 128 + grp * NJP + p];
      UPD(w, x, p * 8, 2)
    }
  }
  const int s3i = (k0 > K12) ? k0 : K12;
#pragma unroll 2
  for (int k = s3i; k < k1; ++k) {
    const float x = hT_old[(k - K12) * B + b];
#pragma unroll
    for (int p = 0; p < NJP; ++p) {
      const uint4 w = wp4[(size_t)k * 128 + grp * NJP + p];
      UPD(w, x, p * 8, 3)
    }
  }
#undef UPD

  float* pw = part + wv * (NJP * 512);
#pragma unroll
  for (int i = 0; i < NJP * 8; ++i) pw[i * 64 + lane] = acc[i];
  __syncthreads();
  for (int idx = tid; idx < NJP * 512; idx += 512) {
    float s = 0.f;
#pragma unroll
    for (int w = 0; w < 8; ++w) s += part[w * (NJP * 512) + idx];
    red[idx] = s;
  }
  __syncthreads();
  if (tid < NJP * 128) {
    const int jl = tid >> 6, ln = tid & 63;
    const int j = grp * (NJP * 2) + jl;
    const int bb = bh * 64 + ln;
    const float az = red[(jl * 4 + 0) * 64 + ln];
    const float ar = red[(jl * 4 + 1) * 64 + ln];
    const float acx = red[(jl * 4 + 2) * 64 + ln];
    const float ach = red[(jl * 4 + 3) * 64 + ln];
    const float z = sigm(az + b3[j]);
    const float r = sigm(ar + b3[H + j]);
    const float c = tanh_(acx + r * ach + b3[2 * H + j]);
    const float hold = hT_old[j * B + bb];
    const float hn = (1.f - z) * hold + z * c;
    hT_new[j * B + bb] = hn;
    if (resOutT) resOutT[j * B + bb] = resInT[j * B + bb] + hn;
  }
}

// dense (512 threads) + alpha finalize for step s, batch row b
__device__ void dense_body(int s, int b, const float* __restrict__ res1T,
                           const float* __restrict__ Wo,
                           const float* __restrict__ bo, float* __restrict__ dout,
                           const float* __restrict__ pvalsS,
                           const float* __restrict__ msS,
                           float* __restrict__ alpha, float* smem) {
  const int tid = threadIdx.x;
  float* red = smem;             // 256
  float* part = smem + 256;      // 512
  if (tid < 256) red[tid] = res1T[tid * B + b];
  __syncthreads();
  {
    const int ks = tid >> 7, c = tid & 127;
    float a = 0.f;
    if (c < D) {
#pragma unroll 8
      for (int k = ks * 64; k < ks * 64 + 64; ++k) a += red[k] * Wo[k * D + c];
    }
    part[ks * 128 + c] = a;
  }
  __syncthreads();
  if (tid < D) {
    float dv = bo[tid];
#pragma unroll
    for (int ks = 0; ks < 4; ++ks) dv += part[ks * 128 + tid];
    const size_t base = (size_t)s * RF * (B * D) + (size_t)b * D + tid;
#pragma unroll
    for (int i = 0; i < RF; ++i)
      __builtin_nontemporal_store(dv, &dout[base + (size_t)i * (B * D)]);
  }
  const float m0 = msS[b], s0 = msS[B + b], m1 = msS[2 * B + b], s1 = msS[3 * B + b];
  const float M = fmaxf(m0, m1);
  const float f0 = __expf(m0 - M), f1 = __expf(m1 - M);
  const float inv = 1.f / (s0 * f0 + s1 * f1);
  const float cc = (tid < 256) ? f0 * inv : f1 * inv;
  __builtin_nontemporal_store(pvalsS[(size_t)b * TIN + tid] * cc,
                              &alpha[((size_t)s * B + b) * TIN + tid]);
}

// attention half (512 threads): qW + e over 256 t's + partial softmax + pctx
__device__ void attn_half_body(int b, int half, const float* __restrict__ qT,
                               const unsigned short* __restrict__ wqB,
                               const float* __restrict__ v_att,
                               const unsigned short* __restrict__ keysB,
                               const unsigned short* __restrict__ memB,
                               float* __restrict__ pvalsS, float* __restrict__ pctxS,
                               float* __restrict__ msS, float* smem) {
  const int tid = threadIdx.x;
  const int lane = tid & 63, wv = tid >> 6;
  const int t0 = half * 256;
  float* hA = smem;              // 256
  float* qk_p = smem + 256;      // 288
  float* v_p = smem + 544;       // 288
  float* scr = smem + 832;       // 4096
  float* ep = smem + 4928;       // 256
  float* r16 = smem + 5184;      // 16
  float* bc = smem + 5200;       // 2

  if (tid < 256) {
    hA[tid] = qT[tid * B + b];
    v_p[(tid >> 4) * 18 + (tid & 15)] = v_att[tid];
  }
  __syncthreads();
  const float4* hA4 = reinterpret_cast<const float4*>(hA);
  const uint4* wQ = reinterpret_cast<const uint4*>(wqB);

  {  // qW: 2-way split-K, 256 cols
    const int c = tid & 255, ks = tid >> 8;
    float a = 0.f;
#pragma unroll
    for (int q = 0; q < 16; ++q) {
      const int kg = ks * 16 + q;
      a += dot8(wQ[(size_t)kg * 256 + c], hA4[kg * 2], hA4[kg * 2 + 1]);
    }
    scr[ks * 256 + c] = a;
  }
  __syncthreads();
  if (tid < 256)
    qk_p[(tid >> 4) * 18 + (tid & 15)] = scr[tid] + scr[256 + tid];
  __syncthreads();

  {  // e-pass: 32 groups x 16 lanes, 8 rows each (2 in flight)
    const int l16 = tid & 15, g = tid >> 4;
    float qg[16], vg[16];
#pragma unroll
    for (int i = 0; i < 16; ++i) {
      qg[i] = qk_p[l16 * 18 + i];
      vg[i] = v_p[l16 * 18 + i];
    }
    const uint4* kB = reinterpret_cast<const uint4*>(keysB + (size_t)b * TIN * H);
#pragma unroll
    for (int p = 0; p < 4; ++p) {
      const int r1 = g + p * 64, r2 = r1 + 32;
      const uint4 a0 = kB[(size_t)(t0 + r1) * 32 + l16 * 2];
      const uint4 a1 = kB[(size_t)(t0 + r1) * 32 + l16 * 2 + 1];
      const uint4 b0 = kB[(size_t)(t0 + r2) * 32 + l16 * 2];
      const uint4 b1 = kB[(size_t)(t0 + r2) * 32 + l16 * 2 + 1];
      float ka[16], kb2[16];
      unpack8(a0, ka); unpack8(a1, ka + 8);
      unpack8(b0, kb2); unpack8(b1, kb2 + 8);
      float s1 = 0.f, s2 = 0.f;
#pragma unroll
      for (int i = 0; i < 16; ++i) {
        s1 += vg[i] * tanh_(ka[i] + qg[i]);
        s2 += vg[i] * tanh_(kb2[i] + qg[i]);
      }
#pragma unroll
      for (int m = 1; m < 16; m <<= 1) { s1 += __shfl_xor(s1, m, 16); s2 += __shfl_xor(s2, m, 16); }
      if (l16 == 0) { ep[r1] = s1; ep[r2] = s2; }
    }
  }
  __syncthreads();

  // partial softmax over 256
  float ev = -1e30f, pv = 0.f;
  if (tid < 256) {
    ev = ep[tid];
    float mx = ev;
#pragma unroll
    for (int m = 1; m < 64; m <<= 1) mx = fmaxf(mx, __shfl_xor(mx, m));
    if (lane == 0) r16[wv] = mx;
  }
  __syncthreads();
  if (tid == 0)
    bc[0] = fmaxf(fmaxf(r16[0], r16[1]), fmaxf(r16[2], r16[3]));
  __syncthreads();
  const float M = bc[0];
  if (tid < 256) {
    pv = __expf(ev - M);
    ep[tid] = pv;
    pvalsS[(size_t)b * TIN + t0 + tid] = pv;
    float s = pv;
#pragma unroll
    for (int m = 1; m < 64; m <<= 1) s += __shfl_xor(s, m);
    if (lane == 0) r16[wv] = s;
  }
  __syncthreads();
  if (tid == 0) {
    msS[half * 2 * B + b] = M;
    msS[(half * 2 + 1) * B + b] = r16[0] + r16[1] + r16[2] + r16[3];
  }

  {  // partial context (unnormalized)
    const int kq8 = tid & 31, ts = tid >> 5;
    float a[8] = {0.f, 0.f, 0.f, 0.f, 0.f, 0.f, 0.f, 0.f};
    const uint4* mB = reinterpret_cast<const uint4*>(memB + (size_t)b * TIN * H);
#pragma unroll 4
    for (int i = 0; i < 16; ++i) {
      const int tt = ts * 16 + i;
      const float p = ep[tt];
      float mv[8];
      unpack8(mB[(size_t)(t0 + tt) * 32 + kq8], mv);
#pragma unroll
      for (int j = 0; j < 8; ++j) a[j] += p * mv[j];
    }
    float4* s4 = reinterpret_cast<float4*>(scr + ts * 256 + kq8 * 8);
    s4[0] = make_float4(a[0], a[1], a[2], a[3]);
    s4[1] = make_float4(a[4], a[5], a[6], a[7]);
  }
  __syncthreads();
  if (tid < 256) {
    float s = 0.f;
#pragma unroll
    for (int ts2 = 0; ts2 < 16; ++ts2) s += scr[ts2 * 256 + tid];
    pctxS[(size_t)(half * 256 + tid) * B + b] = s;
  }
}

// ---------------------------------------------------------------------------
// 5-deep pipeline, 1024 blocks x 512 threads (single scheduling round):
// attn_half(i-1) [0..255], d0(i-2) [256..511], attGRU(i) [512..767],
// d1 NJP=2 (i-3) [768..895], dense+alpha(i-4) [896..1023]. Ring-4 buffers.
__global__ __launch_bounds__(512, 8) void k_pipe(
    int i, const unsigned short* __restrict__ wgA,
    const unsigned short* __restrict__ wg0, const unsigned short* __restrict__ wg1,
    const unsigned short* __restrict__ wqB, const float* __restrict__ v_att,
    const float* __restrict__ b_att, const float* __restrict__ b_d0,
    const float* __restrict__ b_d1, const unsigned short* __restrict__ keysB,
    const unsigned short* __restrict__ memB, const float* __restrict__ preT,
    float* __restrict__ qr, float* __restrict__ hd0r, float* __restrict__ hd1r,
    float* __restrict__ res0r, float* __restrict__ res1r,
    float* __restrict__ pvals, float* __restrict__ pctx, float* __restrict__ ms,
    const float* __restrict__ Wo, const float* __restrict__ bo,
    float* __restrict__ dout, float* __restrict__ alpha) {
  __shared__ alignas(16) float smem[9216];
  const int blk = blockIdx.x;
  if (blk < 256) {                      // attn_half(t = i-1)
    const int t = i - 1;
    if (t >= 0 && t < RSTEPS) {
      const int sl = t & 3;
      attn_half_body(blk >> 1, blk & 1, qr + (size_t)sl * HB, wqB, v_att, keysB,
                     memB, pvals + (size_t)sl * B * TIN,
                     pctx + (size_t)sl * 2 * HB, ms + (size_t)sl * 4 * B, smem);
    }
  } else if (blk < 512) {               // d0(t = i-2), ctx from partials
    const int t = i - 2;
    if (t >= 0 && t < RSTEPS) {
      const int sl = t & 3;
      gru_body<1>(wg0, H, H, H, qr + (size_t)sl * HB, nullptr,
                  pctx + (size_t)sl * 2 * HB, ms + (size_t)sl * 4 * B,
                  hd0r + (size_t)((t + 3) & 3) * HB, b_d0,
                  hd0r + (size_t)sl * HB, qr + (size_t)sl * HB,
                  res0r + (size_t)sl * HB, blk - 256, smem);
    }
  } else if (blk < 768) {               // attGRU(t = i)
    const int t = i;
    if (t < RSTEPS)
      gru_body<1>(wgA, PP, 0, H, preT + (size_t)t * PP * B, nullptr, nullptr,
                  nullptr, qr + (size_t)((t + 3) & 3) * HB, b_att,
                  qr + (size_t)(t & 3) * HB, nullptr, nullptr, blk - 512, smem);
  } else if (blk < 896) {               // d1(t = i-3), 4 j's per block
    const int t = i - 3;
    if (t >= 0 && t < RSTEPS) {
      const int sl = t & 3;
      gru_body<2>(wg1, H, 0, H, res0r + (size_t)sl * HB, nullptr, nullptr,
                  nullptr, hd1r + (size_t)((t + 3) & 3) * HB, b_d1,
                  hd1r + (size_t)sl * HB, res0r + (size_t)sl * HB,
                  res1r + (size_t)sl * HB, blk - 768, smem);
    }
  } else {                              // dense+alpha(t = i-4)
    const int t = i - 4;
    if (t >= 0 && t < RSTEPS) {
      const int sl = t & 3;
      dense_body(t, blk - 896, res1r + (size_t)sl * HB, Wo, bo, dout,
                 pvals + (size_t)sl * B * TIN, ms + (size_t)sl * 4 * B, alpha,
                 smem);
    }
  }
}

// ---------------------------------------------------------------------------
extern "C" void kernel_launch(void* const* d_in, const int* in_sizes, int n_in,
                              void* d_out, int out_size, void* d_ws,
                              size_t ws_size, hipStream_t stream) {
  const float* outs   = (const float*)d_in[0];
  const float* memory = (const float*)d_in[1];
  const float* Wp0    = (const float*)d_in[2];
  const float* bp0    = (const float*)d_in[3];
  const float* Wp1    = (const float*)d_in[4];
  const float* bp1    = (const float*)d_in[5];
  const float* Wx_att = (const float*)d_in[6];
  const float* Wh_att = (const float*)d_in[7];
  const float* b_att  = (const float*)d_in[8];
  const float* Wq     = (const float*)d_in[9];
  const float* Wm     = (const float*)d_in[10];
  const float* v_att  = (const float*)d_in[11];
  const float* Wx_d0  = (const float*)d_in[12];
  const float* Wh_d0  = (const float*)d_in[13];
  const float* b_d0   = (const float*)d_in[14];
  const float* Wx_d1  = (const float*)d_in[15];
  const float* Wh_d1  = (const float*)d_in[16];
  const float* b_d1   = (const float*)d_in[17];
  const float* Wo     = (const float*)d_in[18];
  const float* bo     = (const float*)d_in[19];
  float* dout = (float*)d_out;
  float* wsf  = (float*)d_ws;

  size_t off = 0;  // in floats
  unsigned short* keysB = (unsigned short*)(wsf + off); off += (size_t)TIN * B * H / 2;
  unsigned short* memB  = (unsigned short*)(wsf + off); off += (size_t)TIN * B * H / 2;
  unsigned short* wqB   = (unsigned short*)(wsf + off); off += (size_t)256 * 256 / 2;
  unsigned short* wgA   = (unsigned short*)(wsf + off); off += (size_t)384 * 1024 / 2;
  unsigned short* wg0   = (unsigned short*)(wsf + off); off += (size_t)768 * 1024 / 2;
  unsigned short* wg1   = (unsigned short*)(wsf + off); off += (size_t)512 * 1024 / 2;
  float* preT  = wsf + off; off += (size_t)RSTEPS * PP * B;
  float* qr    = wsf + off; off += (size_t)4 * HB;
  float* hd0r  = wsf + off; off += (size_t)4 * HB;
  float* hd1r  = wsf + off; off += (size_t)4 * HB;
  float* res0r = wsf + off; off += (size_t)4 * HB;
  float* res1r = wsf + off; off += (size_t)4 * HB;
  float* pvals = wsf + off; off += (size_t)4 * B * TIN;
  float* pctx  = wsf + off; off += (size_t)4 * 2 * HB;
  float* ms    = wsf + off; off += (size_t)4 * 4 * B;

  // zero ring slots read at the pipeline head: state(-1) lives in slot 3
  hipMemsetAsync(qr + 3 * HB, 0, (size_t)HB * sizeof(float), stream);
  hipMemsetAsync(hd0r + 3 * HB, 0, (size_t)HB * sizeof(float), stream);
  hipMemsetAsync(hd1r + 3 * HB, 0, (size_t)HB * sizeof(float), stream);

  k_keys<<<B * 16, 256, 0, stream>>>(memory, Wm, keysB, memB);
  k_prenet<<<RSTEPS * B, 256, 0, stream>>>(outs, Wp0, bp0, Wp1, bp1, preT);
  k_packWq<<<256, 256, 0, stream>>>(Wq, wqB);
  k_packG<<<(128 * 768 + 255) / 256, 256, 0, stream>>>(Wx_att, wgA, 128, 0);
  k_packG<<<(256 * 768 + 255) / 256, 256, 0, stream>>>(Wh_att, wgA, 256, 128);
  k_packG<<<(512 * 768 + 255) / 256, 256, 0, stream>>>(Wx_d0, wg0, 512, 0);
  k_packG<<<(256 * 768 + 255) / 256, 256, 0, stream>>>(Wh_d0, wg0, 256, 512);
  k_packG<<<(256 * 768 + 255) / 256, 256, 0, stream>>>(Wx_d1, wg1, 256, 0);
  k_packG<<<(256 * 768 + 255) / 256, 256, 0, stream>>>(Wh_d1, wg1, 256, 256);

  float* alpha = dout + (size_t)1000 * B * D;

  for (int i = 0; i < RSTEPS + 4; ++i) {
    k_pipe<<<1024, 512, 0, stream>>>(i, wgA, wg0, wg1, wqB, v_att, b_att,
                                     b_d0, b_d1, keysB, memB, preT, qr, hd0r,
                                     hd1r, res0r, res1r, pvals, pctx, ms, Wo,
                                     bo, dout, alpha);
  }
}